// Round 10
// baseline (337.089 us; speedup 1.0000x reference)
//
#include <hip/hip_runtime.h>
#include <hip/hip_fp16.h>
#include <math.h>

// ---------------------------------------------------------------------------
// GNN pool: 2x GCNConv(elu) + MLP(128) + Linear(15) + softmax
// N=100000, E=3200000, IN=3, HID=64, MLP_HID=128, K=15, fp32 in/out.
//
// Round-10 pipeline (6 dispatches):
//   prep (cursor=0, W2t/Wm1t fp16 transpose) -> scatter (bucket by dst>>7)
//   -> csr_sort (self-computed bucket prefix [no bscan], counting sort,
//      dis + sxh fp16) -> agg3 (wave/node, 8B gathers, s1 fp16)
//   -> agg64 (2 nodes/wave, PAIRED gathers: 1 instr = 2 edges, half4/lane,
//      __hadd2 pairwise + fp32 acc, shfl_xor(16) combine)
//   -> h1 (MFMA 16x16x32_f16 A/B stages + fused stage-C logits/softmax -> out)
//
// r9 lesson: agg64 sits at the per-CU VMEM throughput ceiling (~10.6 B/cyc/CU
// = copy-kernel rate); bytes & instruction count are the levers, locality is
// not (L3 backs everything). fp8 fails error budget. So: halve instructions,
// keep bytes. Head: m never leaves LDS anymore.
// ---------------------------------------------------------------------------

#define SPAN 128          // nodes per bucket
#define CAP  4608         // bucket capacity (mean 4092 + ~8 sigma)
#define CH   4096         // edges per scatter chunk (782 chunks = 3 blk/CU)
#define EPT  16           // edges per thread in scatter
#define H2P  88           // h2s row pad (halfs)
#define MSP2 136          // ms row pad (halfs)

typedef _Float16 v8hf __attribute__((ext_vector_type(8)));
typedef float    v4f  __attribute__((ext_vector_type(4)));

__device__ __forceinline__ float elu(float v) { return v > 0.f ? v : expm1f(v); }

// ---- prep: zero cursor; W2t[f][k]=fp16(W2[k][f]); Wm1t[j][f]=fp16(Wm1[f][j]) ----
__global__ __launch_bounds__(256) void prep_kernel(const float* __restrict__ W2,
    const float* __restrict__ Wm1, __half* __restrict__ W2t, __half* __restrict__ Wm1t,
    int* __restrict__ cursor, int NBK) {
    int tid = blockIdx.x * 256 + threadIdx.x;
    if (tid < NBK) cursor[tid] = 0;
    if (tid < 64 * 64) {
        int f = tid >> 6, k = tid & 63;
        W2t[f * 64 + k] = __float2half(W2[k * 64 + f]);
    }
    if (tid < 128 * 64) {
        int j = tid >> 6, f = tid & 63;
        Wm1t[j * 64 + f] = __float2half(Wm1[f * 128 + j]);
    }
}

// ---- counting scatter: edges -> buckets by dst>>7, packed (dl<<17)|src ----
__global__ __launch_bounds__(256) void scatter_kernel(const int* __restrict__ src,
    const int* __restrict__ dst, int* __restrict__ cursor, unsigned* __restrict__ colb,
    int E, int NBK) {
    __shared__ int hist[1024];
    __shared__ unsigned gb[1024];
    int tid = threadIdx.x;
    int chunk = blockIdx.x;
    for (int i = tid; i < NBK; i += 256) hist[i] = 0;
    __syncthreads();
    int base = chunk * CH;
    int cnt = min(CH, E - base);
    unsigned br[EPT], dt[EPT];
#pragma unroll
    for (int j = 0; j < EPT; ++j) {
        int idx = j * 256 + tid;
        br[j] = 0xFFFFFFFFu;
        if (idx < cnt) {
            int e = base + idx;
            int s = src[e], d = dst[e];
            int b = d >> 7;
            int r = atomicAdd(&hist[b], 1);
            br[j] = ((unsigned)b << 13) | (unsigned)r;
            dt[j] = ((unsigned)(d & 127) << 17) | (unsigned)s;
        }
    }
    __syncthreads();
    for (int b = tid; b < NBK; b += 256) {
        int c = hist[b];
        gb[b] = (unsigned)(b * CAP) + (c ? (unsigned)atomicAdd(&cursor[b], c) : 0u);
    }
    __syncthreads();
#pragma unroll
    for (int j = 0; j < EPT; ++j) {
        if (br[j] != 0xFFFFFFFFu) {
            int b = br[j] >> 13;
            int r = br[j] & 8191;
            unsigned pos = gb[b] + (unsigned)r;
            if (pos < (unsigned)(b + 1) * CAP) colb[pos] = dt[j];
        }
    }
}

// ---- per-bucket counting sort: self-prefix, row_ptr, dis, sxh, coalesced col ----
__global__ __launch_bounds__(256) void csr_sort_kernel(const unsigned* __restrict__ colb,
    const int* __restrict__ cursor, const float* __restrict__ x,
    int* __restrict__ row_ptr, int* __restrict__ col,
    float* __restrict__ dis, __half* __restrict__ sxh, int N, int NBK) {
    __shared__ unsigned ebuf[CAP];
    __shared__ int sbuf[CAP];
    __shared__ int cnt[SPAN], pref[SPAN], fill[SPAN];
    __shared__ int redbuf[256];
    int b = blockIdx.x, tid = threadIdx.x;
    int n = min(cursor[b], CAP);
    int base = b * CAP;
    // bucket base offset = sum_{i<b} min(cursor[i], CAP)
    int partial = 0;
    for (int i2 = tid; i2 < b; i2 += 256) partial += min(cursor[i2], CAP);
    redbuf[tid] = partial;
    if (tid < SPAN) cnt[tid] = 0;
    for (int i = tid; i < n; i += 256) ebuf[i] = colb[base + i];
    __syncthreads();
    for (int off = 128; off; off >>= 1) {
        if (tid < off) redbuf[tid] += redbuf[tid + off];
        __syncthreads();
    }
    int bb = redbuf[0];
    for (int i = tid; i < n; i += 256) atomicAdd(&cnt[(ebuf[i] >> 17) & 127], 1);
    __syncthreads();
    if (tid < SPAN) pref[tid] = cnt[tid];
    __syncthreads();
    for (int off = 1; off < SPAN; off <<= 1) {
        int xv = (tid < SPAN && tid >= off) ? pref[tid - off] : 0;
        __syncthreads();
        if (tid < SPAN) pref[tid] += xv;
        __syncthreads();
    }
    if (tid < SPAN) {
        int ex = pref[tid] - cnt[tid];
        fill[tid] = ex;
        int node = b * SPAN + tid;
        if (node < N) {
            row_ptr[node] = bb + ex;
            float r = rsqrtf((float)(cnt[tid] + 1));
            dis[node] = r;
            __half2 h0 = __floats2half2_rn(r * x[node * 3 + 0], r * x[node * 3 + 1]);
            __half2 h1 = __floats2half2_rn(r * x[node * 3 + 2], 0.f);
            uint2 w; w.x = *(unsigned*)&h0; w.y = *(unsigned*)&h1;
            *(uint2*)(sxh + (size_t)node * 4) = w;
        }
    }
    if (b == NBK - 1 && tid == 0) row_ptr[N] = bb + n;
    __syncthreads();
    for (int i = tid; i < n; i += 256) {
        unsigned e = ebuf[i];
        int pos = atomicAdd(&fill[(e >> 17) & 127], 1);
        sbuf[pos] = (int)(e & 0x1FFFF);
    }
    __syncthreads();
    for (int i = tid; i < n; i += 256) col[bb + i] = sbuf[i];
}

// ---- layer 1: aggregate sxh (8B) + W1 + bias + elu; s1h = fp16(dis*h1) ----
__global__ void agg3_kernel(const __half* __restrict__ sxh, const int* __restrict__ row_ptr,
                            const int* __restrict__ col, const float* __restrict__ dis,
                            const float* __restrict__ W1, const float* __restrict__ b1,
                            __half* __restrict__ s1h, int N) {
    int wave = (blockIdx.x * blockDim.x + threadIdx.x) >> 6;
    int lane = threadIdx.x & 63;
    if (wave >= N) return;
    int d = wave;
    int start = row_ptr[d], end = row_ptr[d + 1];
    float a0 = 0.f, a1 = 0.f, a2v = 0.f;
    for (int i = start + lane; i < end; i += 64) {
        uint2 rq = *(const uint2*)(sxh + (size_t)col[i] * 4);
        float2 u0 = __half22float2(*(__half2*)&rq.x);
        float2 u1 = __half22float2(*(__half2*)&rq.y);
        a0 += u0.x; a1 += u0.y; a2v += u1.x;
    }
#pragma unroll
    for (int off = 32; off; off >>= 1) {
        a0  += __shfl_xor(a0, off);
        a1  += __shfl_xor(a1, off);
        a2v += __shfl_xor(a2v, off);
    }
    {   // self loop
        uint2 rq = *(const uint2*)(sxh + (size_t)d * 4);
        float2 u0 = __half22float2(*(__half2*)&rq.x);
        float2 u1 = __half22float2(*(__half2*)&rq.y);
        a0 += u0.x; a1 += u0.y; a2v += u1.x;
    }
    float r = dis[d];
    float v = r * (a0 * W1[lane] + a1 * W1[64 + lane] + a2v * W1[128 + lane]) + b1[lane];
    s1h[(size_t)d * 64 + lane] = __float2half(r * elu(v));
}

// ---- layer 2: 2 nodes/wave; lane = 4-feat quad; 1 mem instr = 2 edges ----
__global__ void agg64_kernel(const __half* __restrict__ s1h, const int* __restrict__ row_ptr,
                             const int* __restrict__ col, const float* __restrict__ dis,
                             __half* __restrict__ a2h, int N) {
    int wave = (blockIdx.x * blockDim.x + threadIdx.x) >> 6;
    int lane = threadIdx.x & 63;
    int hl = lane & 31;
    int sub = hl >> 4;        // which edge of the pair this lane serves
    int fl  = hl & 15;        // feature quad: feats 4*fl .. 4*fl+3
    int d = wave * 2 + (lane >> 5);
    bool act = d < N;
    int start = 0, end = 0;
    if (act) { start = row_ptr[d]; end = row_ptr[d + 1]; }
    float ax = 0.f, ay = 0.f, az = 0.f, aw = 0.f;
    int i = start;
    for (; i + 7 < end; i += 8) {
#pragma unroll
        for (int qq = 0; qq < 2; ++qq) {
            int c0 = col[i + 4 * qq + sub];
            int c1 = col[i + 4 * qq + 2 + sub];
            uint2 r0 = *(const uint2*)(s1h + (size_t)c0 * 64 + fl * 4);
            uint2 r1 = *(const uint2*)(s1h + (size_t)c1 * 64 + fl * 4);
            __half2 p0 = __hadd2(*(__half2*)&r0.x, *(__half2*)&r1.x);
            __half2 p1 = __hadd2(*(__half2*)&r0.y, *(__half2*)&r1.y);
            float2 u0 = __half22float2(p0);
            float2 u1 = __half22float2(p1);
            ax += u0.x; ay += u0.y; az += u1.x; aw += u1.y;
        }
    }
    for (; i < end; ++i) {   // remainder: sub==0 lanes only
        if (sub == 0) {
            uint2 r0 = *(const uint2*)(s1h + (size_t)col[i] * 64 + fl * 4);
            float2 u0 = __half22float2(*(__half2*)&r0.x);
            float2 u1 = __half22float2(*(__half2*)&r0.y);
            ax += u0.x; ay += u0.y; az += u1.x; aw += u1.y;
        }
    }
    ax += __shfl_xor(ax, 16);
    ay += __shfl_xor(ay, 16);
    az += __shfl_xor(az, 16);
    aw += __shfl_xor(aw, 16);
    if (act && sub == 0) {
        uint2 r0 = *(const uint2*)(s1h + (size_t)d * 64 + fl * 4);   // self loop
        float2 u0 = __half22float2(*(__half2*)&r0.x);
        float2 u1 = __half22float2(*(__half2*)&r0.y);
        float rd = dis[d];
        __half2 o0 = __floats2half2_rn(rd * (ax + u0.x), rd * (ay + u0.y));
        __half2 o1 = __floats2half2_rn(rd * (az + u1.x), rd * (aw + u1.y));
        uint2 w; w.x = *(unsigned*)&o0; w.y = *(unsigned*)&o1;
        *(uint2*)(a2h + (size_t)d * 64 + fl * 4) = w;
    }
}

// ---- h1 (MFMA + fused head): out = softmax(elu(elu(a2h@W2)@Wm1)@Wm2) ----
// Block = 64 nodes. Stage A/B: mfma_f32_16x16x32_f16 (r9-verified layouts).
// Stage C: logits from ms (LDS) + Wt2 (fp32 LDS), softmax, direct out write.
__global__ __launch_bounds__(256) void h1_kernel(const __half* __restrict__ a2h,
    const __half* __restrict__ W2t, const float* __restrict__ b2g,
    const __half* __restrict__ Wm1t, const float* __restrict__ bm1g,
    const float* __restrict__ Wm2g, const float* __restrict__ bm2g,
    float* __restrict__ out, int N) {
    __shared__ __align__(16) __half h2s[64 * H2P];   // 11.3 KB
    __shared__ __align__(16) __half ms[64 * MSP2];   // 17.4 KB
    __shared__ float Wt2[15 * 128];                  // 7.7 KB, [c][j]
    __shared__ float lgs[16 * 16];
    __shared__ float b2s[64], bm1s[128], bm2s[16];
    int tid = threadIdx.x;
    if (tid < 64)  b2s[tid]  = b2g[tid];
    if (tid < 128) bm1s[tid] = bm1g[tid];
    if (tid < 16)  bm2s[tid] = (tid < 15) ? bm2g[tid] : 0.f;
    for (int i = tid; i < 15 * 128; i += 256) {
        int c = i >> 7, j = i & 127;
        Wt2[i] = Wm2g[j * 15 + c];
    }
    __syncthreads();

    int wave = tid >> 6, lane = tid & 63;
    int q = lane >> 4, l16 = lane & 15;
    int base = blockIdx.x * 64;

    // ---- stage A: D[m=node16][n=f] = a2h @ W2 ----
    {
        int nodeRow = base + wave * 16 + l16;
        size_t arow = (size_t)min(nodeRow, N - 1) * 64;
        v8hf af0 = *(const v8hf*)(a2h + arow + q * 8);
        v8hf af1 = *(const v8hf*)(a2h + arow + 32 + q * 8);
#pragma unroll
        for (int fb = 0; fb < 4; ++fb) {
            float bb = b2s[fb * 16 + l16];
            v4f acc = {bb, bb, bb, bb};
            v8hf b0 = *(const v8hf*)(W2t + (fb * 16 + l16) * 64 + q * 8);
            v8hf b1 = *(const v8hf*)(W2t + (fb * 16 + l16) * 64 + 32 + q * 8);
            acc = __builtin_amdgcn_mfma_f32_16x16x32_f16(af0, b0, acc, 0, 0, 0);
            acc = __builtin_amdgcn_mfma_f32_16x16x32_f16(af1, b1, acc, 0, 0, 0);
#pragma unroll
            for (int r = 0; r < 4; ++r)
                h2s[(wave * 16 + q * 4 + r) * H2P + fb * 16 + l16] =
                    __float2half(elu(acc[r]));
        }
    }
    __syncthreads();
    // ---- stage B: D[m=node16][n=j] = h2 @ Wm1 ----
    {
        int arow = (wave * 16 + l16) * H2P;
        v8hf af0 = *(const v8hf*)(h2s + arow + q * 8);
        v8hf af1 = *(const v8hf*)(h2s + arow + 32 + q * 8);
#pragma unroll
        for (int jb = 0; jb < 8; ++jb) {
            float bb = bm1s[jb * 16 + l16];
            v4f acc = {bb, bb, bb, bb};
            v8hf b0 = *(const v8hf*)(Wm1t + (jb * 16 + l16) * 64 + q * 8);
            v8hf b1 = *(const v8hf*)(Wm1t + (jb * 16 + l16) * 64 + 32 + q * 8);
            acc = __builtin_amdgcn_mfma_f32_16x16x32_f16(af0, b0, acc, 0, 0, 0);
            acc = __builtin_amdgcn_mfma_f32_16x16x32_f16(af1, b1, acc, 0, 0, 0);
#pragma unroll
            for (int r = 0; r < 4; ++r)
                ms[(wave * 16 + q * 4 + r) * MSP2 + jb * 16 + l16] =
                    __float2half(elu(acc[r]));
        }
    }
    __syncthreads();
    // ---- stage C: logits + softmax, 16 nodes x 15 classes per iteration ----
    {
        int cc = tid % 15;
        int nn = tid / 15;
        bool actC = tid < 240;
#pragma unroll
        for (int it = 0; it < 4; ++it) {
            if (actC) {
                int row = it * 16 + nn;
                float acc = bm2s[cc];
                const __half2* mrow = (const __half2*)(ms + row * MSP2);
                const float* wrow = Wt2 + cc * 128;
#pragma unroll 4
                for (int j2 = 0; j2 < 64; ++j2) {
                    float2 u = __half22float2(mrow[j2]);
                    acc = fmaf(u.x, wrow[2 * j2], fmaf(u.y, wrow[2 * j2 + 1], acc));
                }
                lgs[nn * 16 + cc] = acc;
            }
            __syncthreads();
            if (actC) {
                int node = base + it * 16 + nn;
                float mx = lgs[nn * 16 + 0];
#pragma unroll
                for (int c2 = 1; c2 < 15; ++c2) mx = fmaxf(mx, lgs[nn * 16 + c2]);
                float sden = 0.f;
#pragma unroll
                for (int c2 = 0; c2 < 15; ++c2) sden += __expf(lgs[nn * 16 + c2] - mx);
                if (node < N)
                    out[(size_t)node * 15 + cc] = __expf(lgs[nn * 16 + cc] - mx) / sden;
            }
            __syncthreads();
        }
    }
}

extern "C" void kernel_launch(void* const* d_in, const int* in_sizes, int n_in,
                              void* d_out, int out_size, void* d_ws, size_t ws_size,
                              hipStream_t stream) {
    const float* x   = (const float*)d_in[0];
    const int*   ei  = (const int*)d_in[1];
    const float* W1  = (const float*)d_in[2];
    const float* b1  = (const float*)d_in[3];
    const float* W2  = (const float*)d_in[4];
    const float* b2  = (const float*)d_in[5];
    const float* Wm1 = (const float*)d_in[6];
    const float* bm1 = (const float*)d_in[7];
    const float* Wm2 = (const float*)d_in[8];
    const float* bm2 = (const float*)d_in[9];
    float* out = (float*)d_out;

    int N = in_sizes[0] / 3;
    int E = in_sizes[1] / 2;
    const int* src = ei;
    const int* dst = ei + E;
    int NBK = (N + SPAN - 1) / SPAN;   // 782

    uintptr_t p = (uintptr_t)d_ws;
    auto carve = [&](size_t bytes) -> void* {
        p = (p + 255) & ~(uintptr_t)255;
        void* r = (void*)p;
        p += bytes;
        return r;
    };
    __half*   a2h     = (__half*)carve((size_t)N * 64 * 2);    // colb aliases a2h+s1h
    __half*   s1h     = (__half*)carve((size_t)N * 64 * 2);
    int*      cursor  = (int*)carve((size_t)NBK * 4);
    int*      row_ptr = (int*)carve((size_t)(N + 1) * 4);
    float*    dis     = (float*)carve((size_t)N * 4);
    __half*   sxh     = (__half*)carve((size_t)N * 8);
    int*      col     = (int*)carve((size_t)E * 4);
    __half*   W2t     = (__half*)carve(64 * 64 * 2);
    __half*   Wm1t    = (__half*)carve(128 * 64 * 2);
    // colb (14.4 MB) aliases [a2h|s1h] (25.6 MB contiguous): colb dead after
    // csr_sort; s1h written in agg3, a2h in agg64 — both after.
    unsigned* colb = (unsigned*)a2h;

    int nChunks = (E + CH - 1) / CH;          // 782
    int waveBlocks3  = (N + 3) / 4;           // agg3: 1 node/wave
    int waveBlocks64 = (N + 7) / 8;           // agg64: 2 nodes/wave
    int nTiles = (N + 63) / 64;               // h1: 64-node tiles
    prep_kernel<<<32, 256, 0, stream>>>(W2, Wm1, W2t, Wm1t, cursor, NBK);
    scatter_kernel<<<nChunks, 256, 0, stream>>>(src, dst, cursor, colb, E, NBK);
    csr_sort_kernel<<<NBK, 256, 0, stream>>>(colb, cursor, x, row_ptr, col, dis, sxh, N, NBK);
    agg3_kernel<<<waveBlocks3, 256, 0, stream>>>(sxh, row_ptr, col, dis, W1, b1, s1h, N);
    agg64_kernel<<<waveBlocks64, 256, 0, stream>>>(s1h, row_ptr, col, dis, a2h, N);
    h1_kernel<<<nTiles, 256, 0, stream>>>(a2h, W2t, b2, Wm1t, bm1, Wm2, bm2, out, N);
}

// Round 11
// 279.551 us; speedup vs baseline: 1.2058x; 1.2058x over previous
//
#include <hip/hip_runtime.h>
#include <hip/hip_fp16.h>
#include <math.h>

// ---------------------------------------------------------------------------
// GNN pool: 2x GCNConv(elu) + MLP(128) + Linear(15) + softmax
// N=100000, E=3200000, IN=3, HID=64, MLP_HID=128, K=15, fp32 in/out.
//
// Round-11 pipeline (6 dispatches):
//   prep (cursor=0, W2t/Wm1t fp16 transpose) -> scatter (bucket by dst>>7)
//   -> csr_sort (self-prefix, counting sort, dis + sxh fp16)
//   -> agg3 (wave/node, 8B gathers, s1 fp16)
//   -> agg64 (2 nodes/wave, paired gathers: 1 instr = 2 edges)
//   -> h1 (MFMA A/B stages + fused stage-C logits/softmax -> out)
//
// r10 lesson: stage C's Wt2[c][j] layout had row stride 128 ≡ 0 mod 32 ->
// the 15 class-lanes serialized 15-way on every read (39.2M conflict cycles
// ≈ 64 us). Fix: Wt2[j][16] (class-fastest, stride 16) -> 15 consecutive
// banks, conflict-free. Everything else unchanged from r10.
// ---------------------------------------------------------------------------

#define SPAN 128          // nodes per bucket
#define CAP  4608         // bucket capacity (mean 4092 + ~8 sigma)
#define CH   4096         // edges per scatter chunk (782 chunks = 3 blk/CU)
#define EPT  16           // edges per thread in scatter
#define H2P  88           // h2s row pad (halfs)
#define MSP2 136          // ms row pad (halfs)

typedef _Float16 v8hf __attribute__((ext_vector_type(8)));
typedef float    v4f  __attribute__((ext_vector_type(4)));

__device__ __forceinline__ float elu(float v) { return v > 0.f ? v : expm1f(v); }

// ---- prep: zero cursor; W2t[f][k]=fp16(W2[k][f]); Wm1t[j][f]=fp16(Wm1[f][j]) ----
__global__ __launch_bounds__(256) void prep_kernel(const float* __restrict__ W2,
    const float* __restrict__ Wm1, __half* __restrict__ W2t, __half* __restrict__ Wm1t,
    int* __restrict__ cursor, int NBK) {
    int tid = blockIdx.x * 256 + threadIdx.x;
    if (tid < NBK) cursor[tid] = 0;
    if (tid < 64 * 64) {
        int f = tid >> 6, k = tid & 63;
        W2t[f * 64 + k] = __float2half(W2[k * 64 + f]);
    }
    if (tid < 128 * 64) {
        int j = tid >> 6, f = tid & 63;
        Wm1t[j * 64 + f] = __float2half(Wm1[f * 128 + j]);
    }
}

// ---- counting scatter: edges -> buckets by dst>>7, packed (dl<<17)|src ----
__global__ __launch_bounds__(256) void scatter_kernel(const int* __restrict__ src,
    const int* __restrict__ dst, int* __restrict__ cursor, unsigned* __restrict__ colb,
    int E, int NBK) {
    __shared__ int hist[1024];
    __shared__ unsigned gb[1024];
    int tid = threadIdx.x;
    int chunk = blockIdx.x;
    for (int i = tid; i < NBK; i += 256) hist[i] = 0;
    __syncthreads();
    int base = chunk * CH;
    int cnt = min(CH, E - base);
    unsigned br[EPT], dt[EPT];
#pragma unroll
    for (int j = 0; j < EPT; ++j) {
        int idx = j * 256 + tid;
        br[j] = 0xFFFFFFFFu;
        if (idx < cnt) {
            int e = base + idx;
            int s = src[e], d = dst[e];
            int b = d >> 7;
            int r = atomicAdd(&hist[b], 1);
            br[j] = ((unsigned)b << 13) | (unsigned)r;
            dt[j] = ((unsigned)(d & 127) << 17) | (unsigned)s;
        }
    }
    __syncthreads();
    for (int b = tid; b < NBK; b += 256) {
        int c = hist[b];
        gb[b] = (unsigned)(b * CAP) + (c ? (unsigned)atomicAdd(&cursor[b], c) : 0u);
    }
    __syncthreads();
#pragma unroll
    for (int j = 0; j < EPT; ++j) {
        if (br[j] != 0xFFFFFFFFu) {
            int b = br[j] >> 13;
            int r = br[j] & 8191;
            unsigned pos = gb[b] + (unsigned)r;
            if (pos < (unsigned)(b + 1) * CAP) colb[pos] = dt[j];
        }
    }
}

// ---- per-bucket counting sort: self-prefix, row_ptr, dis, sxh, coalesced col ----
__global__ __launch_bounds__(256) void csr_sort_kernel(const unsigned* __restrict__ colb,
    const int* __restrict__ cursor, const float* __restrict__ x,
    int* __restrict__ row_ptr, int* __restrict__ col,
    float* __restrict__ dis, __half* __restrict__ sxh, int N, int NBK) {
    __shared__ unsigned ebuf[CAP];
    __shared__ int sbuf[CAP];
    __shared__ int cnt[SPAN], pref[SPAN], fill[SPAN];
    __shared__ int redbuf[256];
    int b = blockIdx.x, tid = threadIdx.x;
    int n = min(cursor[b], CAP);
    int base = b * CAP;
    int partial = 0;
    for (int i2 = tid; i2 < b; i2 += 256) partial += min(cursor[i2], CAP);
    redbuf[tid] = partial;
    if (tid < SPAN) cnt[tid] = 0;
    for (int i = tid; i < n; i += 256) ebuf[i] = colb[base + i];
    __syncthreads();
    for (int off = 128; off; off >>= 1) {
        if (tid < off) redbuf[tid] += redbuf[tid + off];
        __syncthreads();
    }
    int bb = redbuf[0];
    for (int i = tid; i < n; i += 256) atomicAdd(&cnt[(ebuf[i] >> 17) & 127], 1);
    __syncthreads();
    if (tid < SPAN) pref[tid] = cnt[tid];
    __syncthreads();
    for (int off = 1; off < SPAN; off <<= 1) {
        int xv = (tid < SPAN && tid >= off) ? pref[tid - off] : 0;
        __syncthreads();
        if (tid < SPAN) pref[tid] += xv;
        __syncthreads();
    }
    if (tid < SPAN) {
        int ex = pref[tid] - cnt[tid];
        fill[tid] = ex;
        int node = b * SPAN + tid;
        if (node < N) {
            row_ptr[node] = bb + ex;
            float r = rsqrtf((float)(cnt[tid] + 1));
            dis[node] = r;
            __half2 h0 = __floats2half2_rn(r * x[node * 3 + 0], r * x[node * 3 + 1]);
            __half2 h1 = __floats2half2_rn(r * x[node * 3 + 2], 0.f);
            uint2 w; w.x = *(unsigned*)&h0; w.y = *(unsigned*)&h1;
            *(uint2*)(sxh + (size_t)node * 4) = w;
        }
    }
    if (b == NBK - 1 && tid == 0) row_ptr[N] = bb + n;
    __syncthreads();
    for (int i = tid; i < n; i += 256) {
        unsigned e = ebuf[i];
        int pos = atomicAdd(&fill[(e >> 17) & 127], 1);
        sbuf[pos] = (int)(e & 0x1FFFF);
    }
    __syncthreads();
    for (int i = tid; i < n; i += 256) col[bb + i] = sbuf[i];
}

// ---- layer 1: aggregate sxh (8B) + W1 + bias + elu; s1h = fp16(dis*h1) ----
__global__ void agg3_kernel(const __half* __restrict__ sxh, const int* __restrict__ row_ptr,
                            const int* __restrict__ col, const float* __restrict__ dis,
                            const float* __restrict__ W1, const float* __restrict__ b1,
                            __half* __restrict__ s1h, int N) {
    int wave = (blockIdx.x * blockDim.x + threadIdx.x) >> 6;
    int lane = threadIdx.x & 63;
    if (wave >= N) return;
    int d = wave;
    int start = row_ptr[d], end = row_ptr[d + 1];
    float a0 = 0.f, a1 = 0.f, a2v = 0.f;
    for (int i = start + lane; i < end; i += 64) {
        uint2 rq = *(const uint2*)(sxh + (size_t)col[i] * 4);
        float2 u0 = __half22float2(*(__half2*)&rq.x);
        float2 u1 = __half22float2(*(__half2*)&rq.y);
        a0 += u0.x; a1 += u0.y; a2v += u1.x;
    }
#pragma unroll
    for (int off = 32; off; off >>= 1) {
        a0  += __shfl_xor(a0, off);
        a1  += __shfl_xor(a1, off);
        a2v += __shfl_xor(a2v, off);
    }
    {   // self loop
        uint2 rq = *(const uint2*)(sxh + (size_t)d * 4);
        float2 u0 = __half22float2(*(__half2*)&rq.x);
        float2 u1 = __half22float2(*(__half2*)&rq.y);
        a0 += u0.x; a1 += u0.y; a2v += u1.x;
    }
    float r = dis[d];
    float v = r * (a0 * W1[lane] + a1 * W1[64 + lane] + a2v * W1[128 + lane]) + b1[lane];
    s1h[(size_t)d * 64 + lane] = __float2half(r * elu(v));
}

// ---- layer 2: 2 nodes/wave; lane = 4-feat quad; 1 mem instr = 2 edges ----
__global__ void agg64_kernel(const __half* __restrict__ s1h, const int* __restrict__ row_ptr,
                             const int* __restrict__ col, const float* __restrict__ dis,
                             __half* __restrict__ a2h, int N) {
    int wave = (blockIdx.x * blockDim.x + threadIdx.x) >> 6;
    int lane = threadIdx.x & 63;
    int hl = lane & 31;
    int sub = hl >> 4;
    int fl  = hl & 15;
    int d = wave * 2 + (lane >> 5);
    bool act = d < N;
    int start = 0, end = 0;
    if (act) { start = row_ptr[d]; end = row_ptr[d + 1]; }
    float ax = 0.f, ay = 0.f, az = 0.f, aw = 0.f;
    int i = start;
    for (; i + 7 < end; i += 8) {
#pragma unroll
        for (int qq = 0; qq < 2; ++qq) {
            int c0 = col[i + 4 * qq + sub];
            int c1 = col[i + 4 * qq + 2 + sub];
            uint2 r0 = *(const uint2*)(s1h + (size_t)c0 * 64 + fl * 4);
            uint2 r1 = *(const uint2*)(s1h + (size_t)c1 * 64 + fl * 4);
            __half2 p0 = __hadd2(*(__half2*)&r0.x, *(__half2*)&r1.x);
            __half2 p1 = __hadd2(*(__half2*)&r0.y, *(__half2*)&r1.y);
            float2 u0 = __half22float2(p0);
            float2 u1 = __half22float2(p1);
            ax += u0.x; ay += u0.y; az += u1.x; aw += u1.y;
        }
    }
    for (; i < end; ++i) {
        if (sub == 0) {
            uint2 r0 = *(const uint2*)(s1h + (size_t)col[i] * 64 + fl * 4);
            float2 u0 = __half22float2(*(__half2*)&r0.x);
            float2 u1 = __half22float2(*(__half2*)&r0.y);
            ax += u0.x; ay += u0.y; az += u1.x; aw += u1.y;
        }
    }
    ax += __shfl_xor(ax, 16);
    ay += __shfl_xor(ay, 16);
    az += __shfl_xor(az, 16);
    aw += __shfl_xor(aw, 16);
    if (act && sub == 0) {
        uint2 r0 = *(const uint2*)(s1h + (size_t)d * 64 + fl * 4);   // self loop
        float2 u0 = __half22float2(*(__half2*)&r0.x);
        float2 u1 = __half22float2(*(__half2*)&r0.y);
        float rd = dis[d];
        __half2 o0 = __floats2half2_rn(rd * (ax + u0.x), rd * (ay + u0.y));
        __half2 o1 = __floats2half2_rn(rd * (az + u1.x), rd * (aw + u1.y));
        uint2 w; w.x = *(unsigned*)&o0; w.y = *(unsigned*)&o1;
        *(uint2*)(a2h + (size_t)d * 64 + fl * 4) = w;
    }
}

// ---- h1 (MFMA + fused head): out = softmax(elu(elu(a2h@W2)@Wm1)@Wm2) ----
// Stage C weight tile Wt2[j][16] (class-fastest, stride 16): the 15
// class-lanes hit consecutive banks -> conflict-free (r10's [c][j] layout
// had stride 128 ≡ 0 mod 32 -> 15-way conflicts, 39M cycles).
__global__ __launch_bounds__(256) void h1_kernel(const __half* __restrict__ a2h,
    const __half* __restrict__ W2t, const float* __restrict__ b2g,
    const __half* __restrict__ Wm1t, const float* __restrict__ bm1g,
    const float* __restrict__ Wm2g, const float* __restrict__ bm2g,
    float* __restrict__ out, int N) {
    __shared__ __align__(16) __half h2s[64 * H2P];   // 11.3 KB
    __shared__ __align__(16) __half ms[64 * MSP2];   // 17.4 KB
    __shared__ float Wt2[128 * 16];                  // 8 KB, [j][c] c-fast
    __shared__ float lgs[16 * 16];
    __shared__ float b2s[64], bm1s[128], bm2s[16];
    int tid = threadIdx.x;
    if (tid < 64)  b2s[tid]  = b2g[tid];
    if (tid < 128) bm1s[tid] = bm1g[tid];
    if (tid < 16)  bm2s[tid] = (tid < 15) ? bm2g[tid] : 0.f;
    for (int i = tid; i < 128 * 16; i += 256) {
        int j = i >> 4, c = i & 15;
        Wt2[i] = (c < 15) ? Wm2g[j * 15 + c] : 0.f;
    }
    __syncthreads();

    int wave = tid >> 6, lane = tid & 63;
    int q = lane >> 4, l16 = lane & 15;
    int base = blockIdx.x * 64;

    // ---- stage A: D[m=node16][n=f] = a2h @ W2 ----
    {
        int nodeRow = base + wave * 16 + l16;
        size_t arow = (size_t)min(nodeRow, N - 1) * 64;
        v8hf af0 = *(const v8hf*)(a2h + arow + q * 8);
        v8hf af1 = *(const v8hf*)(a2h + arow + 32 + q * 8);
#pragma unroll
        for (int fb = 0; fb < 4; ++fb) {
            float bb = b2s[fb * 16 + l16];
            v4f acc = {bb, bb, bb, bb};
            v8hf b0 = *(const v8hf*)(W2t + (fb * 16 + l16) * 64 + q * 8);
            v8hf b1 = *(const v8hf*)(W2t + (fb * 16 + l16) * 64 + 32 + q * 8);
            acc = __builtin_amdgcn_mfma_f32_16x16x32_f16(af0, b0, acc, 0, 0, 0);
            acc = __builtin_amdgcn_mfma_f32_16x16x32_f16(af1, b1, acc, 0, 0, 0);
#pragma unroll
            for (int r = 0; r < 4; ++r)
                h2s[(wave * 16 + q * 4 + r) * H2P + fb * 16 + l16] =
                    __float2half(elu(acc[r]));
        }
    }
    __syncthreads();
    // ---- stage B: D[m=node16][n=j] = h2 @ Wm1 ----
    {
        int arow = (wave * 16 + l16) * H2P;
        v8hf af0 = *(const v8hf*)(h2s + arow + q * 8);
        v8hf af1 = *(const v8hf*)(h2s + arow + 32 + q * 8);
#pragma unroll
        for (int jb = 0; jb < 8; ++jb) {
            float bb = bm1s[jb * 16 + l16];
            v4f acc = {bb, bb, bb, bb};
            v8hf b0 = *(const v8hf*)(Wm1t + (jb * 16 + l16) * 64 + q * 8);
            v8hf b1 = *(const v8hf*)(Wm1t + (jb * 16 + l16) * 64 + 32 + q * 8);
            acc = __builtin_amdgcn_mfma_f32_16x16x32_f16(af0, b0, acc, 0, 0, 0);
            acc = __builtin_amdgcn_mfma_f32_16x16x32_f16(af1, b1, acc, 0, 0, 0);
#pragma unroll
            for (int r = 0; r < 4; ++r)
                ms[(wave * 16 + q * 4 + r) * MSP2 + jb * 16 + l16] =
                    __float2half(elu(acc[r]));
        }
    }
    __syncthreads();
    // ---- stage C: logits + softmax, 16 nodes x 15 classes per iteration ----
    {
        int cc = tid % 15;
        int nn = tid / 15;
        bool actC = tid < 240;
#pragma unroll
        for (int it = 0; it < 4; ++it) {
            if (actC) {
                int row = it * 16 + nn;
                float acc = bm2s[cc];
                const __half2* mrow = (const __half2*)(ms + row * MSP2);
#pragma unroll 4
                for (int j2 = 0; j2 < 64; ++j2) {
                    float2 u = __half22float2(mrow[j2]);
                    acc = fmaf(u.x, Wt2[(2 * j2) * 16 + cc],
                          fmaf(u.y, Wt2[(2 * j2 + 1) * 16 + cc], acc));
                }
                lgs[nn * 16 + cc] = acc;
            }
            __syncthreads();
            if (actC) {
                int node = base + it * 16 + nn;
                float mx = lgs[nn * 16 + 0];
#pragma unroll
                for (int c2 = 1; c2 < 15; ++c2) mx = fmaxf(mx, lgs[nn * 16 + c2]);
                float sden = 0.f;
#pragma unroll
                for (int c2 = 0; c2 < 15; ++c2) sden += __expf(lgs[nn * 16 + c2] - mx);
                if (node < N)
                    out[(size_t)node * 15 + cc] = __expf(lgs[nn * 16 + cc] - mx) / sden;
            }
            __syncthreads();
        }
    }
}

extern "C" void kernel_launch(void* const* d_in, const int* in_sizes, int n_in,
                              void* d_out, int out_size, void* d_ws, size_t ws_size,
                              hipStream_t stream) {
    const float* x   = (const float*)d_in[0];
    const int*   ei  = (const int*)d_in[1];
    const float* W1  = (const float*)d_in[2];
    const float* b1  = (const float*)d_in[3];
    const float* W2  = (const float*)d_in[4];
    const float* b2  = (const float*)d_in[5];
    const float* Wm1 = (const float*)d_in[6];
    const float* bm1 = (const float*)d_in[7];
    const float* Wm2 = (const float*)d_in[8];
    const float* bm2 = (const float*)d_in[9];
    float* out = (float*)d_out;

    int N = in_sizes[0] / 3;
    int E = in_sizes[1] / 2;
    const int* src = ei;
    const int* dst = ei + E;
    int NBK = (N + SPAN - 1) / SPAN;   // 782

    uintptr_t p = (uintptr_t)d_ws;
    auto carve = [&](size_t bytes) -> void* {
        p = (p + 255) & ~(uintptr_t)255;
        void* r = (void*)p;
        p += bytes;
        return r;
    };
    __half*   a2h     = (__half*)carve((size_t)N * 64 * 2);    // colb aliases a2h+s1h
    __half*   s1h     = (__half*)carve((size_t)N * 64 * 2);
    int*      cursor  = (int*)carve((size_t)NBK * 4);
    int*      row_ptr = (int*)carve((size_t)(N + 1) * 4);
    float*    dis     = (float*)carve((size_t)N * 4);
    __half*   sxh     = (__half*)carve((size_t)N * 8);
    int*      col     = (int*)carve((size_t)E * 4);
    __half*   W2t     = (__half*)carve(64 * 64 * 2);
    __half*   Wm1t    = (__half*)carve(128 * 64 * 2);
    unsigned* colb = (unsigned*)a2h;   // dead after csr_sort; rewritten later

    int nChunks = (E + CH - 1) / CH;          // 782
    int waveBlocks3  = (N + 3) / 4;           // agg3: 1 node/wave
    int waveBlocks64 = (N + 7) / 8;           // agg64: 2 nodes/wave
    int nTiles = (N + 63) / 64;               // h1: 64-node tiles
    prep_kernel<<<32, 256, 0, stream>>>(W2, Wm1, W2t, Wm1t, cursor, NBK);
    scatter_kernel<<<nChunks, 256, 0, stream>>>(src, dst, cursor, colb, E, NBK);
    csr_sort_kernel<<<NBK, 256, 0, stream>>>(colb, cursor, x, row_ptr, col, dis, sxh, N, NBK);
    agg3_kernel<<<waveBlocks3, 256, 0, stream>>>(sxh, row_ptr, col, dis, W1, b1, s1h, N);
    agg64_kernel<<<waveBlocks64, 256, 0, stream>>>(s1h, row_ptr, col, dis, a2h, N);
    h1_kernel<<<nTiles, 256, 0, stream>>>(a2h, W2t, b2, Wm1t, bm1, Wm2, bm2, out, N);
}

// Round 12
// 267.884 us; speedup vs baseline: 1.2583x; 1.0436x over previous
//
#include <hip/hip_runtime.h>
#include <hip/hip_fp16.h>
#include <math.h>

// ---------------------------------------------------------------------------
// GNN pool: 2x GCNConv(elu) + MLP(128) + Linear(15) + softmax
// N=100000, E=3200000, IN=3, HID=64, MLP_HID=128, K=15, fp32 in/out.
//
// Round-12 pipeline (6 dispatches):
//   prep (cursor=0, W2t/Wm1t fp16 transpose) -> scatter (bucket by dst>>7,
//   CH=8192: ~10-entry write runs) -> csr_sort (self-prefix counting sort)
//   -> agg3 (wave/node, 8B gathers, s1 fp16)
//   -> agg64 (r9 form: 2 nodes/wave, half2 gathers — measured-best 63us;
//      r11's paired-gather variant proved instruction count is NOT the
//      bottleneck: bytes are, 410 MB @ ~6.3 TB/s = structural floor)
//   -> h1 (MFMA A/B + stage-C logits with 16-lane shfl softmax: no LDS
//      round-trip, no barriers in epilogue)
// ---------------------------------------------------------------------------

#define SPAN 128          // nodes per bucket
#define CAP  4608         // bucket capacity (mean 4092 + ~8 sigma)
#define CH   8192         // edges per scatter chunk (391 blocks)
#define EPT  32           // edges per thread in scatter
#define H2P  88           // h2s row pad (halfs)
#define MSP2 136          // ms row pad (halfs)

typedef _Float16 v8hf __attribute__((ext_vector_type(8)));
typedef float    v4f  __attribute__((ext_vector_type(4)));

__device__ __forceinline__ float elu(float v) { return v > 0.f ? v : expm1f(v); }

// ---- prep: zero cursor; W2t[f][k]=fp16(W2[k][f]); Wm1t[j][f]=fp16(Wm1[f][j]) ----
__global__ __launch_bounds__(256) void prep_kernel(const float* __restrict__ W2,
    const float* __restrict__ Wm1, __half* __restrict__ W2t, __half* __restrict__ Wm1t,
    int* __restrict__ cursor, int NBK) {
    int tid = blockIdx.x * 256 + threadIdx.x;
    if (tid < NBK) cursor[tid] = 0;
    if (tid < 64 * 64) {
        int f = tid >> 6, k = tid & 63;
        W2t[f * 64 + k] = __float2half(W2[k * 64 + f]);
    }
    if (tid < 128 * 64) {
        int j = tid >> 6, f = tid & 63;
        Wm1t[j * 64 + f] = __float2half(Wm1[f * 128 + j]);
    }
}

// ---- counting scatter: edges -> buckets by dst>>7, packed (dl<<17)|src ----
__global__ __launch_bounds__(256) void scatter_kernel(const int* __restrict__ src,
    const int* __restrict__ dst, int* __restrict__ cursor, unsigned* __restrict__ colb,
    int E, int NBK) {
    __shared__ int hist[1024];
    __shared__ unsigned gb[1024];
    int tid = threadIdx.x;
    int chunk = blockIdx.x;
    for (int i = tid; i < NBK; i += 256) hist[i] = 0;
    __syncthreads();
    int base = chunk * CH;
    int cnt = min(CH, E - base);
    unsigned br[EPT], dt[EPT];
#pragma unroll
    for (int j = 0; j < EPT; ++j) {
        int idx = j * 256 + tid;
        br[j] = 0xFFFFFFFFu;
        if (idx < cnt) {
            int e = base + idx;
            int s = src[e], d = dst[e];
            int b = d >> 7;
            int r = atomicAdd(&hist[b], 1);
            br[j] = ((unsigned)b << 13) | (unsigned)r;   // b<1024(10b), r<8192(13b)
            dt[j] = ((unsigned)(d & 127) << 17) | (unsigned)s;
        }
    }
    __syncthreads();
    for (int b = tid; b < NBK; b += 256) {
        int c = hist[b];
        gb[b] = (unsigned)(b * CAP) + (c ? (unsigned)atomicAdd(&cursor[b], c) : 0u);
    }
    __syncthreads();
#pragma unroll
    for (int j = 0; j < EPT; ++j) {
        if (br[j] != 0xFFFFFFFFu) {
            int b = br[j] >> 13;
            int r = br[j] & 8191;
            unsigned pos = gb[b] + (unsigned)r;
            if (pos < (unsigned)(b + 1) * CAP) colb[pos] = dt[j];
        }
    }
}

// ---- per-bucket counting sort: self-prefix, row_ptr, dis, sxh, coalesced col ----
__global__ __launch_bounds__(256) void csr_sort_kernel(const unsigned* __restrict__ colb,
    const int* __restrict__ cursor, const float* __restrict__ x,
    int* __restrict__ row_ptr, int* __restrict__ col,
    float* __restrict__ dis, __half* __restrict__ sxh, int N, int NBK) {
    __shared__ unsigned ebuf[CAP];
    __shared__ int sbuf[CAP];
    __shared__ int cnt[SPAN], pref[SPAN], fill[SPAN];
    __shared__ int redbuf[256];
    int b = blockIdx.x, tid = threadIdx.x;
    int n = min(cursor[b], CAP);
    int base = b * CAP;
    int partial = 0;
    for (int i2 = tid; i2 < b; i2 += 256) partial += min(cursor[i2], CAP);
    redbuf[tid] = partial;
    if (tid < SPAN) cnt[tid] = 0;
    for (int i = tid; i < n; i += 256) ebuf[i] = colb[base + i];
    __syncthreads();
    for (int off = 128; off; off >>= 1) {
        if (tid < off) redbuf[tid] += redbuf[tid + off];
        __syncthreads();
    }
    int bb = redbuf[0];
    for (int i = tid; i < n; i += 256) atomicAdd(&cnt[(ebuf[i] >> 17) & 127], 1);
    __syncthreads();
    if (tid < SPAN) pref[tid] = cnt[tid];
    __syncthreads();
    for (int off = 1; off < SPAN; off <<= 1) {
        int xv = (tid < SPAN && tid >= off) ? pref[tid - off] : 0;
        __syncthreads();
        if (tid < SPAN) pref[tid] += xv;
        __syncthreads();
    }
    if (tid < SPAN) {
        int ex = pref[tid] - cnt[tid];
        fill[tid] = ex;
        int node = b * SPAN + tid;
        if (node < N) {
            row_ptr[node] = bb + ex;
            float r = rsqrtf((float)(cnt[tid] + 1));
            dis[node] = r;
            __half2 h0 = __floats2half2_rn(r * x[node * 3 + 0], r * x[node * 3 + 1]);
            __half2 h1 = __floats2half2_rn(r * x[node * 3 + 2], 0.f);
            uint2 w; w.x = *(unsigned*)&h0; w.y = *(unsigned*)&h1;
            *(uint2*)(sxh + (size_t)node * 4) = w;
        }
    }
    if (b == NBK - 1 && tid == 0) row_ptr[N] = bb + n;
    __syncthreads();
    for (int i = tid; i < n; i += 256) {
        unsigned e = ebuf[i];
        int pos = atomicAdd(&fill[(e >> 17) & 127], 1);
        sbuf[pos] = (int)(e & 0x1FFFF);
    }
    __syncthreads();
    for (int i = tid; i < n; i += 256) col[bb + i] = sbuf[i];
}

// ---- layer 1: aggregate sxh (8B) + W1 + bias + elu; s1h = fp16(dis*h1) ----
__global__ void agg3_kernel(const __half* __restrict__ sxh, const int* __restrict__ row_ptr,
                            const int* __restrict__ col, const float* __restrict__ dis,
                            const float* __restrict__ W1, const float* __restrict__ b1,
                            __half* __restrict__ s1h, int N) {
    int wave = (blockIdx.x * blockDim.x + threadIdx.x) >> 6;
    int lane = threadIdx.x & 63;
    if (wave >= N) return;
    int d = wave;
    int start = row_ptr[d], end = row_ptr[d + 1];
    float a0 = 0.f, a1 = 0.f, a2v = 0.f;
    for (int i = start + lane; i < end; i += 64) {
        uint2 rq = *(const uint2*)(sxh + (size_t)col[i] * 4);
        float2 u0 = __half22float2(*(__half2*)&rq.x);
        float2 u1 = __half22float2(*(__half2*)&rq.y);
        a0 += u0.x; a1 += u0.y; a2v += u1.x;
    }
#pragma unroll
    for (int off = 32; off; off >>= 1) {
        a0  += __shfl_xor(a0, off);
        a1  += __shfl_xor(a1, off);
        a2v += __shfl_xor(a2v, off);
    }
    {   // self loop
        uint2 rq = *(const uint2*)(sxh + (size_t)d * 4);
        float2 u0 = __half22float2(*(__half2*)&rq.x);
        float2 u1 = __half22float2(*(__half2*)&rq.y);
        a0 += u0.x; a1 += u0.y; a2v += u1.x;
    }
    float r = dis[d];
    float v = r * (a0 * W1[lane] + a1 * W1[64 + lane] + a2v * W1[128 + lane]) + b1[lane];
    s1h[(size_t)d * 64 + lane] = __float2half(r * elu(v));
}

// ---- layer 2 (r9 form): 2 nodes/wave, half2 gathers, fp32 accum, fp16 out ----
__global__ void agg64_kernel(const __half2* __restrict__ s1h, const int* __restrict__ row_ptr,
                             const int* __restrict__ col, const float* __restrict__ dis,
                             __half2* __restrict__ a2h, int N) {
    int wave = (blockIdx.x * blockDim.x + threadIdx.x) >> 6;
    int lane = threadIdx.x & 63;
    int hl = lane & 31;
    int d = wave * 2 + (lane >> 5);
    bool act = d < N;
    int start = 0, end = 0;
    if (act) { start = row_ptr[d]; end = row_ptr[d + 1]; }
    float a0x = 0.f, a0y = 0.f, a1x = 0.f, a1y = 0.f;
    float a2x = 0.f, a2y = 0.f, a3x = 0.f, a3y = 0.f;
    float a4x = 0.f, a4y = 0.f, a5x = 0.f, a5y = 0.f;
    float a6x = 0.f, a6y = 0.f, a7x = 0.f, a7y = 0.f;
    if (act) {   // self loop
        float2 v = __half22float2(s1h[(size_t)d * 32 + hl]);
        a0x = v.x; a0y = v.y;
    }
    int i = start;
    for (; i + 7 < end; i += 8) {
        int c0 = col[i],     c1 = col[i + 1], c2 = col[i + 2], c3 = col[i + 3];
        int c4 = col[i + 4], c5 = col[i + 5], c6 = col[i + 6], c7 = col[i + 7];
        float2 v0 = __half22float2(s1h[(size_t)c0 * 32 + hl]);
        float2 v1 = __half22float2(s1h[(size_t)c1 * 32 + hl]);
        float2 v2 = __half22float2(s1h[(size_t)c2 * 32 + hl]);
        float2 v3 = __half22float2(s1h[(size_t)c3 * 32 + hl]);
        float2 v4 = __half22float2(s1h[(size_t)c4 * 32 + hl]);
        float2 v5 = __half22float2(s1h[(size_t)c5 * 32 + hl]);
        float2 v6 = __half22float2(s1h[(size_t)c6 * 32 + hl]);
        float2 v7 = __half22float2(s1h[(size_t)c7 * 32 + hl]);
        a0x += v0.x; a0y += v0.y; a1x += v1.x; a1y += v1.y;
        a2x += v2.x; a2y += v2.y; a3x += v3.x; a3y += v3.y;
        a4x += v4.x; a4y += v4.y; a5x += v5.x; a5y += v5.y;
        a6x += v6.x; a6y += v6.y; a7x += v7.x; a7y += v7.y;
    }
    for (; i < end; ++i) {
        float2 v = __half22float2(s1h[(size_t)col[i] * 32 + hl]);
        a0x += v.x; a0y += v.y;
    }
    if (act) {
        float r = dis[d];
        float ox = r * (((a0x + a1x) + (a2x + a3x)) + ((a4x + a5x) + (a6x + a7x)));
        float oy = r * (((a0y + a1y) + (a2y + a3y)) + ((a4y + a5y) + (a6y + a7y)));
        a2h[(size_t)d * 32 + hl] = __floats2half2_rn(ox, oy);
    }
}

// ---- h1 (MFMA + fused head): out = softmax(elu(elu(a2h@W2)@Wm1)@Wm2) ----
// Stage C: lane = nloc*16 + c (c=15 idle); logits from ms (broadcast reads)
// + Wt2[j][16] (conflict-free); softmax via shfl_xor{1,2,4,8} in 16-lane
// groups — no LDS round-trip, no barriers in the epilogue.
__global__ __launch_bounds__(256) void h1_kernel(const __half* __restrict__ a2h,
    const __half* __restrict__ W2t, const float* __restrict__ b2g,
    const __half* __restrict__ Wm1t, const float* __restrict__ bm1g,
    const float* __restrict__ Wm2g, const float* __restrict__ bm2g,
    float* __restrict__ out, int N) {
    __shared__ __align__(16) __half h2s[64 * H2P];   // 11.3 KB
    __shared__ __align__(16) __half ms[64 * MSP2];   // 17.4 KB
    __shared__ float Wt2[128 * 16];                  // 8 KB, [j][c] c-fast
    __shared__ float b2s[64], bm1s[128], bm2s[16];
    int tid = threadIdx.x;
    if (tid < 64)  b2s[tid]  = b2g[tid];
    if (tid < 128) bm1s[tid] = bm1g[tid];
    if (tid < 16)  bm2s[tid] = (tid < 15) ? bm2g[tid] : 0.f;
    for (int i = tid; i < 128 * 16; i += 256) {
        int j = i >> 4, c = i & 15;
        Wt2[i] = (c < 15) ? Wm2g[j * 15 + c] : 0.f;
    }
    __syncthreads();

    int wave = tid >> 6, lane = tid & 63;
    int q = lane >> 4, l16 = lane & 15;
    int base = blockIdx.x * 64;

    // ---- stage A: D[m=node16][n=f] = a2h @ W2 ----
    {
        int nodeRow = base + wave * 16 + l16;
        size_t arow = (size_t)min(nodeRow, N - 1) * 64;
        v8hf af0 = *(const v8hf*)(a2h + arow + q * 8);
        v8hf af1 = *(const v8hf*)(a2h + arow + 32 + q * 8);
#pragma unroll
        for (int fb = 0; fb < 4; ++fb) {
            float bb = b2s[fb * 16 + l16];
            v4f acc = {bb, bb, bb, bb};
            v8hf b0 = *(const v8hf*)(W2t + (fb * 16 + l16) * 64 + q * 8);
            v8hf b1 = *(const v8hf*)(W2t + (fb * 16 + l16) * 64 + 32 + q * 8);
            acc = __builtin_amdgcn_mfma_f32_16x16x32_f16(af0, b0, acc, 0, 0, 0);
            acc = __builtin_amdgcn_mfma_f32_16x16x32_f16(af1, b1, acc, 0, 0, 0);
#pragma unroll
            for (int r = 0; r < 4; ++r)
                h2s[(wave * 16 + q * 4 + r) * H2P + fb * 16 + l16] =
                    __float2half(elu(acc[r]));
        }
    }
    __syncthreads();
    // ---- stage B: D[m=node16][n=j] = h2 @ Wm1 ----
    {
        int arow = (wave * 16 + l16) * H2P;
        v8hf af0 = *(const v8hf*)(h2s + arow + q * 8);
        v8hf af1 = *(const v8hf*)(h2s + arow + 32 + q * 8);
#pragma unroll
        for (int jb = 0; jb < 8; ++jb) {
            float bb = bm1s[jb * 16 + l16];
            v4f acc = {bb, bb, bb, bb};
            v8hf b0 = *(const v8hf*)(Wm1t + (jb * 16 + l16) * 64 + q * 8);
            v8hf b1 = *(const v8hf*)(Wm1t + (jb * 16 + l16) * 64 + 32 + q * 8);
            acc = __builtin_amdgcn_mfma_f32_16x16x32_f16(af0, b0, acc, 0, 0, 0);
            acc = __builtin_amdgcn_mfma_f32_16x16x32_f16(af1, b1, acc, 0, 0, 0);
#pragma unroll
            for (int r = 0; r < 4; ++r)
                ms[(wave * 16 + q * 4 + r) * MSP2 + jb * 16 + l16] =
                    __float2half(elu(acc[r]));
        }
    }
    __syncthreads();
    // ---- stage C: logits + shfl softmax; lane = nloc*16 + c ----
    {
        int c = l16;                 // class 0..14 (15 idle for logits)
        int nloc = wave * 4 + q;     // node-slot 0..15
#pragma unroll
        for (int it = 0; it < 4; ++it) {
            int row = it * 16 + nloc;
            float acc = bm2s[c];
            const __half2* mrow = (const __half2*)(ms + row * MSP2);
#pragma unroll 4
            for (int j2 = 0; j2 < 64; ++j2) {
                float2 u = __half22float2(mrow[j2]);
                acc = fmaf(u.x, Wt2[(2 * j2) * 16 + c],
                      fmaf(u.y, Wt2[(2 * j2 + 1) * 16 + c], acc));
            }
            float lg = (c < 15) ? acc : -1e30f;
            float mx = lg;
            mx = fmaxf(mx, __shfl_xor(mx, 1));
            mx = fmaxf(mx, __shfl_xor(mx, 2));
            mx = fmaxf(mx, __shfl_xor(mx, 4));
            mx = fmaxf(mx, __shfl_xor(mx, 8));
            float ex = (c < 15) ? __expf(lg - mx) : 0.f;
            float sden = ex;
            sden += __shfl_xor(sden, 1);
            sden += __shfl_xor(sden, 2);
            sden += __shfl_xor(sden, 4);
            sden += __shfl_xor(sden, 8);
            int node = base + row;
            if (c < 15 && node < N)
                out[(size_t)node * 15 + c] = ex / sden;
        }
    }
}

extern "C" void kernel_launch(void* const* d_in, const int* in_sizes, int n_in,
                              void* d_out, int out_size, void* d_ws, size_t ws_size,
                              hipStream_t stream) {
    const float* x   = (const float*)d_in[0];
    const int*   ei  = (const int*)d_in[1];
    const float* W1  = (const float*)d_in[2];
    const float* b1  = (const float*)d_in[3];
    const float* W2  = (const float*)d_in[4];
    const float* b2  = (const float*)d_in[5];
    const float* Wm1 = (const float*)d_in[6];
    const float* bm1 = (const float*)d_in[7];
    const float* Wm2 = (const float*)d_in[8];
    const float* bm2 = (const float*)d_in[9];
    float* out = (float*)d_out;

    int N = in_sizes[0] / 3;
    int E = in_sizes[1] / 2;
    const int* src = ei;
    const int* dst = ei + E;
    int NBK = (N + SPAN - 1) / SPAN;   // 782

    uintptr_t p = (uintptr_t)d_ws;
    auto carve = [&](size_t bytes) -> void* {
        p = (p + 255) & ~(uintptr_t)255;
        void* r = (void*)p;
        p += bytes;
        return r;
    };
    __half*   a2h     = (__half*)carve((size_t)N * 64 * 2);    // colb aliases a2h+s1h
    __half*   s1h     = (__half*)carve((size_t)N * 64 * 2);
    int*      cursor  = (int*)carve((size_t)NBK * 4);
    int*      row_ptr = (int*)carve((size_t)(N + 1) * 4);
    float*    dis     = (float*)carve((size_t)N * 4);
    __half*   sxh     = (__half*)carve((size_t)N * 8);
    int*      col     = (int*)carve((size_t)E * 4);
    __half*   W2t     = (__half*)carve(64 * 64 * 2);
    __half*   Wm1t    = (__half*)carve(128 * 64 * 2);
    unsigned* colb = (unsigned*)a2h;   // dead after csr_sort; rewritten later

    int nChunks = (E + CH - 1) / CH;          // 391
    int waveBlocks3  = (N + 3) / 4;           // agg3: 1 node/wave
    int waveBlocks64 = (N + 7) / 8;           // agg64: 2 nodes/wave
    int nTiles = (N + 63) / 64;               // h1: 64-node tiles
    prep_kernel<<<32, 256, 0, stream>>>(W2, Wm1, W2t, Wm1t, cursor, NBK);
    scatter_kernel<<<nChunks, 256, 0, stream>>>(src, dst, cursor, colb, E, NBK);
    csr_sort_kernel<<<NBK, 256, 0, stream>>>(colb, cursor, x, row_ptr, col, dis, sxh, N, NBK);
    agg3_kernel<<<waveBlocks3, 256, 0, stream>>>(sxh, row_ptr, col, dis, W1, b1, s1h, N);
    agg64_kernel<<<waveBlocks64, 256, 0, stream>>>((const __half2*)s1h, row_ptr, col, dis,
                                                   (__half2*)a2h, N);
    h1_kernel<<<nTiles, 256, 0, stream>>>(a2h, W2t, b2, Wm1t, bm1, Wm2, bm2, out, N);
}

// Round 13
// 246.736 us; speedup vs baseline: 1.3662x; 1.0857x over previous
//
#include <hip/hip_runtime.h>
#include <hip/hip_fp16.h>
#include <math.h>

// ---------------------------------------------------------------------------
// GNN pool: 2x GCNConv(elu) + MLP(128) + Linear(15) + softmax
// N=100000, E=3200000, IN=3, HID=64, MLP_HID=128, K=15, fp32 in/out.
//
// Round-13 pipeline (6 dispatches incl. memset):
//   memset cursor -> scatter512 (+prep block: W2t/Wm1t/Wm2p fp16)
//   -> csr_sort (self-prefix counting sort) -> agg3 (wave/node, s1 fp16)
//   -> agg64 (r9 form — measured floor ~62.5us: per-CU delivered-bytes bound)
//   -> h1 (all-MFMA: stage A 8, stage B 16, stage C 4 mfma (K=128, packed
//      Wm2 fragments in VGPRs) + shfl softmax -> out)
//
// r12 lessons: agg64 at 410 MB gather = 10.7 B/cyc/CU (m13 ceiling) is the
// structural floor; r11 proved instr count isn't the lever. h1's scalar
// stage-C (512 FMA + 256 LDS reads per lane) dwarfed its 24 MFMAs -> MFMA it.
// Scatter at 1.5 blocks/CU was latency-starved -> 512 threads.
// ---------------------------------------------------------------------------

#define SPAN 128          // nodes per bucket
#define CAP  4608         // bucket capacity (mean 4092 + ~8 sigma)
#define CH   8192         // edges per scatter chunk (391 chunks)
#define EPT  16           // edges per thread in scatter (512 threads)
#define H2P  88           // h2s row pad (halfs) — 176 B rows, 16B aligned
#define MSP2 136          // ms row pad (halfs) — 272 B rows, 16B aligned

typedef _Float16 v8hf __attribute__((ext_vector_type(8)));
typedef float    v4f  __attribute__((ext_vector_type(4)));

__device__ __forceinline__ float elu(float v) { return v > 0.f ? v : expm1f(v); }

// ---- scatter (512 thr): edges -> buckets by dst>>7; last block = weight prep ----
__global__ __launch_bounds__(512) void scatter_kernel(const int* __restrict__ src,
    const int* __restrict__ dst, int* __restrict__ cursor, unsigned* __restrict__ colb,
    const float* __restrict__ W2, const float* __restrict__ Wm1,
    const float* __restrict__ Wm2, __half* __restrict__ W2t,
    __half* __restrict__ Wm1t, __half* __restrict__ Wm2p,
    int E, int NBK, int nChunks) {
    int tid = threadIdx.x;
    if ((int)blockIdx.x == nChunks) {   // ---- prep block ----
        for (int i = tid; i < 64 * 64; i += 512) {
            int f = i >> 6, k = i & 63;
            W2t[f * 64 + k] = __float2half(W2[k * 64 + f]);
        }
        for (int i = tid; i < 128 * 64; i += 512) {
            int j = i >> 6, f = i & 63;
            Wm1t[j * 64 + f] = __float2half(Wm1[f * 128 + j]);
        }
        // fragment-order Wm2: Wm2p[(t*64+l)*8+j] = Wm2[(32t+(l>>4)*8+j)*15+c], c=l&15
        for (int i = tid; i < 4 * 64 * 8; i += 512) {
            int j = i & 7, l = (i >> 3) & 63, t = i >> 9;
            int k = t * 32 + (l >> 4) * 8 + j;
            int c = l & 15;
            Wm2p[i] = (c < 15) ? __float2half(Wm2[k * 15 + c]) : __half(0.f);
        }
        return;
    }
    __shared__ int hist[1024];
    __shared__ unsigned gb[1024];
    int chunk = blockIdx.x;
    for (int i = tid; i < NBK; i += 512) hist[i] = 0;
    __syncthreads();
    int base = chunk * CH;
    int cnt = min(CH, E - base);
    unsigned br[EPT], dt[EPT];
#pragma unroll
    for (int j = 0; j < EPT; ++j) {
        int idx = j * 512 + tid;
        br[j] = 0xFFFFFFFFu;
        if (idx < cnt) {
            int e = base + idx;
            int s = src[e], d = dst[e];
            int b = d >> 7;
            int r = atomicAdd(&hist[b], 1);
            br[j] = ((unsigned)b << 13) | (unsigned)r;   // b<1024(10b), r<8192(13b)
            dt[j] = ((unsigned)(d & 127) << 17) | (unsigned)s;
        }
    }
    __syncthreads();
    for (int b = tid; b < NBK; b += 512) {
        int c = hist[b];
        gb[b] = (unsigned)(b * CAP) + (c ? (unsigned)atomicAdd(&cursor[b], c) : 0u);
    }
    __syncthreads();
#pragma unroll
    for (int j = 0; j < EPT; ++j) {
        if (br[j] != 0xFFFFFFFFu) {
            int b = br[j] >> 13;
            int r = br[j] & 8191;
            unsigned pos = gb[b] + (unsigned)r;
            if (pos < (unsigned)(b + 1) * CAP) colb[pos] = dt[j];
        }
    }
}

// ---- per-bucket counting sort: self-prefix, row_ptr, dis, sxh, coalesced col ----
__global__ __launch_bounds__(256) void csr_sort_kernel(const unsigned* __restrict__ colb,
    const int* __restrict__ cursor, const float* __restrict__ x,
    int* __restrict__ row_ptr, int* __restrict__ col,
    float* __restrict__ dis, __half* __restrict__ sxh, int N, int NBK) {
    __shared__ unsigned ebuf[CAP];
    __shared__ int sbuf[CAP];
    __shared__ int cnt[SPAN], pref[SPAN], fill[SPAN];
    __shared__ int redbuf[256];
    int b = blockIdx.x, tid = threadIdx.x;
    int n = min(cursor[b], CAP);
    int base = b * CAP;
    int partial = 0;
    for (int i2 = tid; i2 < b; i2 += 256) partial += min(cursor[i2], CAP);
    redbuf[tid] = partial;
    if (tid < SPAN) cnt[tid] = 0;
    for (int i = tid; i < n; i += 256) ebuf[i] = colb[base + i];
    __syncthreads();
    for (int off = 128; off; off >>= 1) {
        if (tid < off) redbuf[tid] += redbuf[tid + off];
        __syncthreads();
    }
    int bb = redbuf[0];
    for (int i = tid; i < n; i += 256) atomicAdd(&cnt[(ebuf[i] >> 17) & 127], 1);
    __syncthreads();
    if (tid < SPAN) pref[tid] = cnt[tid];
    __syncthreads();
    for (int off = 1; off < SPAN; off <<= 1) {
        int xv = (tid < SPAN && tid >= off) ? pref[tid - off] : 0;
        __syncthreads();
        if (tid < SPAN) pref[tid] += xv;
        __syncthreads();
    }
    if (tid < SPAN) {
        int ex = pref[tid] - cnt[tid];
        fill[tid] = ex;
        int node = b * SPAN + tid;
        if (node < N) {
            row_ptr[node] = bb + ex;
            float r = rsqrtf((float)(cnt[tid] + 1));
            dis[node] = r;
            __half2 h0 = __floats2half2_rn(r * x[node * 3 + 0], r * x[node * 3 + 1]);
            __half2 h1 = __floats2half2_rn(r * x[node * 3 + 2], 0.f);
            uint2 w; w.x = *(unsigned*)&h0; w.y = *(unsigned*)&h1;
            *(uint2*)(sxh + (size_t)node * 4) = w;
        }
    }
    if (b == NBK - 1 && tid == 0) row_ptr[N] = bb + n;
    __syncthreads();
    for (int i = tid; i < n; i += 256) {
        unsigned e = ebuf[i];
        int pos = atomicAdd(&fill[(e >> 17) & 127], 1);
        sbuf[pos] = (int)(e & 0x1FFFF);
    }
    __syncthreads();
    for (int i = tid; i < n; i += 256) col[bb + i] = sbuf[i];
}

// ---- layer 1: aggregate sxh (8B) + W1 + bias + elu; s1h = fp16(dis*h1) ----
__global__ void agg3_kernel(const __half* __restrict__ sxh, const int* __restrict__ row_ptr,
                            const int* __restrict__ col, const float* __restrict__ dis,
                            const float* __restrict__ W1, const float* __restrict__ b1,
                            __half* __restrict__ s1h, int N) {
    int wave = (blockIdx.x * blockDim.x + threadIdx.x) >> 6;
    int lane = threadIdx.x & 63;
    if (wave >= N) return;
    int d = wave;
    int start = row_ptr[d], end = row_ptr[d + 1];
    float a0 = 0.f, a1 = 0.f, a2v = 0.f;
    for (int i = start + lane; i < end; i += 64) {
        uint2 rq = *(const uint2*)(sxh + (size_t)col[i] * 4);
        float2 u0 = __half22float2(*(__half2*)&rq.x);
        float2 u1 = __half22float2(*(__half2*)&rq.y);
        a0 += u0.x; a1 += u0.y; a2v += u1.x;
    }
#pragma unroll
    for (int off = 32; off; off >>= 1) {
        a0  += __shfl_xor(a0, off);
        a1  += __shfl_xor(a1, off);
        a2v += __shfl_xor(a2v, off);
    }
    {   // self loop
        uint2 rq = *(const uint2*)(sxh + (size_t)d * 4);
        float2 u0 = __half22float2(*(__half2*)&rq.x);
        float2 u1 = __half22float2(*(__half2*)&rq.y);
        a0 += u0.x; a1 += u0.y; a2v += u1.x;
    }
    float r = dis[d];
    float v = r * (a0 * W1[lane] + a1 * W1[64 + lane] + a2v * W1[128 + lane]) + b1[lane];
    s1h[(size_t)d * 64 + lane] = __float2half(r * elu(v));
}

// ---- layer 2 (r9 form): 2 nodes/wave, half2 gathers, fp32 accum, fp16 out ----
__global__ void agg64_kernel(const __half2* __restrict__ s1h, const int* __restrict__ row_ptr,
                             const int* __restrict__ col, const float* __restrict__ dis,
                             __half2* __restrict__ a2h, int N) {
    int wave = (blockIdx.x * blockDim.x + threadIdx.x) >> 6;
    int lane = threadIdx.x & 63;
    int hl = lane & 31;
    int d = wave * 2 + (lane >> 5);
    bool act = d < N;
    int start = 0, end = 0;
    if (act) { start = row_ptr[d]; end = row_ptr[d + 1]; }
    float a0x = 0.f, a0y = 0.f, a1x = 0.f, a1y = 0.f;
    float a2x = 0.f, a2y = 0.f, a3x = 0.f, a3y = 0.f;
    float a4x = 0.f, a4y = 0.f, a5x = 0.f, a5y = 0.f;
    float a6x = 0.f, a6y = 0.f, a7x = 0.f, a7y = 0.f;
    if (act) {   // self loop
        float2 v = __half22float2(s1h[(size_t)d * 32 + hl]);
        a0x = v.x; a0y = v.y;
    }
    int i = start;
    for (; i + 7 < end; i += 8) {
        int c0 = col[i],     c1 = col[i + 1], c2 = col[i + 2], c3 = col[i + 3];
        int c4 = col[i + 4], c5 = col[i + 5], c6 = col[i + 6], c7 = col[i + 7];
        float2 v0 = __half22float2(s1h[(size_t)c0 * 32 + hl]);
        float2 v1 = __half22float2(s1h[(size_t)c1 * 32 + hl]);
        float2 v2 = __half22float2(s1h[(size_t)c2 * 32 + hl]);
        float2 v3 = __half22float2(s1h[(size_t)c3 * 32 + hl]);
        float2 v4 = __half22float2(s1h[(size_t)c4 * 32 + hl]);
        float2 v5 = __half22float2(s1h[(size_t)c5 * 32 + hl]);
        float2 v6 = __half22float2(s1h[(size_t)c6 * 32 + hl]);
        float2 v7 = __half22float2(s1h[(size_t)c7 * 32 + hl]);
        a0x += v0.x; a0y += v0.y; a1x += v1.x; a1y += v1.y;
        a2x += v2.x; a2y += v2.y; a3x += v3.x; a3y += v3.y;
        a4x += v4.x; a4y += v4.y; a5x += v5.x; a5y += v5.y;
        a6x += v6.x; a6y += v6.y; a7x += v7.x; a7y += v7.y;
    }
    for (; i < end; ++i) {
        float2 v = __half22float2(s1h[(size_t)col[i] * 32 + hl]);
        a0x += v.x; a0y += v.y;
    }
    if (act) {
        float r = dis[d];
        float ox = r * (((a0x + a1x) + (a2x + a3x)) + ((a4x + a5x) + (a6x + a7x)));
        float oy = r * (((a0y + a1y) + (a2y + a3y)) + ((a4y + a5y) + (a6y + a7y)));
        a2h[(size_t)d * 32 + hl] = __floats2half2_rn(ox, oy);
    }
}

// ---- h1 (all-MFMA): out = softmax(elu(elu(a2h@W2)@Wm1)@Wm2) ----
// Stage A: 8 mfma; Stage B: 16 mfma; Stage C: 4 mfma (K=128) with packed
// Wm2 fragments held in VGPRs; shfl_xor{1,2,4,8} softmax. Biases via L1.
__global__ __launch_bounds__(256) void h1_kernel(const __half* __restrict__ a2h,
    const __half* __restrict__ W2t, const float* __restrict__ b2g,
    const __half* __restrict__ Wm1t, const float* __restrict__ bm1g,
    const __half* __restrict__ Wm2p, const float* __restrict__ bm2g,
    float* __restrict__ out, int N) {
    __shared__ __align__(16) __half h2s[64 * H2P];   // 11.3 KB
    __shared__ __align__(16) __half ms[64 * MSP2];   // 17.4 KB
    int tid = threadIdx.x;
    int wave = tid >> 6, lane = tid & 63;
    int q = lane >> 4, l16 = lane & 15;
    int base = blockIdx.x * 64;

    // prefetch stage-C weight fragments (16 VGPRs) + bias
    v8hf wc[4];
#pragma unroll
    for (int t = 0; t < 4; ++t)
        wc[t] = *(const v8hf*)(Wm2p + ((size_t)(t * 64 + lane)) * 8);
    float bbc = (l16 < 15) ? bm2g[l16] : 0.f;

    // ---- stage A: D[m=node16][n=f] = a2h @ W2 ----
    {
        int nodeRow = base + wave * 16 + l16;
        size_t arow = (size_t)min(nodeRow, N - 1) * 64;
        v8hf af0 = *(const v8hf*)(a2h + arow + q * 8);
        v8hf af1 = *(const v8hf*)(a2h + arow + 32 + q * 8);
#pragma unroll
        for (int fb = 0; fb < 4; ++fb) {
            float bb = b2g[fb * 16 + l16];
            v4f acc = {bb, bb, bb, bb};
            v8hf b0 = *(const v8hf*)(W2t + (fb * 16 + l16) * 64 + q * 8);
            v8hf b1 = *(const v8hf*)(W2t + (fb * 16 + l16) * 64 + 32 + q * 8);
            acc = __builtin_amdgcn_mfma_f32_16x16x32_f16(af0, b0, acc, 0, 0, 0);
            acc = __builtin_amdgcn_mfma_f32_16x16x32_f16(af1, b1, acc, 0, 0, 0);
#pragma unroll
            for (int r = 0; r < 4; ++r)
                h2s[(wave * 16 + q * 4 + r) * H2P + fb * 16 + l16] =
                    __float2half(elu(acc[r]));
        }
    }
    __syncthreads();
    // ---- stage B: D[m=node16][n=j] = h2 @ Wm1 ----
    {
        int arow = (wave * 16 + l16) * H2P;
        v8hf af0 = *(const v8hf*)(h2s + arow + q * 8);
        v8hf af1 = *(const v8hf*)(h2s + arow + 32 + q * 8);
#pragma unroll
        for (int jb = 0; jb < 8; ++jb) {
            float bb = bm1g[jb * 16 + l16];
            v4f acc = {bb, bb, bb, bb};
            v8hf b0 = *(const v8hf*)(Wm1t + (jb * 16 + l16) * 64 + q * 8);
            v8hf b1 = *(const v8hf*)(Wm1t + (jb * 16 + l16) * 64 + 32 + q * 8);
            acc = __builtin_amdgcn_mfma_f32_16x16x32_f16(af0, b0, acc, 0, 0, 0);
            acc = __builtin_amdgcn_mfma_f32_16x16x32_f16(af1, b1, acc, 0, 0, 0);
#pragma unroll
            for (int r = 0; r < 4; ++r)
                ms[(wave * 16 + q * 4 + r) * MSP2 + jb * 16 + l16] =
                    __float2half(elu(acc[r]));
        }
    }
    __syncthreads();
    // ---- stage C: D[m=node16][n=class16] = m @ Wm2 (K=128), then softmax ----
    {
        int arow = (wave * 16 + l16) * MSP2;
        v4f accC = {bbc, bbc, bbc, bbc};
#pragma unroll
        for (int t = 0; t < 4; ++t) {
            v8hf a = *(const v8hf*)(ms + arow + t * 32 + q * 8);
            accC = __builtin_amdgcn_mfma_f32_16x16x32_f16(a, wc[t], accC, 0, 0, 0);
        }
#pragma unroll
        for (int r = 0; r < 4; ++r) {
            float lg = (l16 < 15) ? accC[r] : -1e30f;
            float mx = lg;
            mx = fmaxf(mx, __shfl_xor(mx, 1));
            mx = fmaxf(mx, __shfl_xor(mx, 2));
            mx = fmaxf(mx, __shfl_xor(mx, 4));
            mx = fmaxf(mx, __shfl_xor(mx, 8));
            float ex = (l16 < 15) ? __expf(lg - mx) : 0.f;
            float sden = ex;
            sden += __shfl_xor(sden, 1);
            sden += __shfl_xor(sden, 2);
            sden += __shfl_xor(sden, 4);
            sden += __shfl_xor(sden, 8);
            int node = base + wave * 16 + q * 4 + r;
            if (l16 < 15 && node < N)
                out[(size_t)node * 15 + l16] = ex / sden;
        }
    }
}

extern "C" void kernel_launch(void* const* d_in, const int* in_sizes, int n_in,
                              void* d_out, int out_size, void* d_ws, size_t ws_size,
                              hipStream_t stream) {
    const float* x   = (const float*)d_in[0];
    const int*   ei  = (const int*)d_in[1];
    const float* W1  = (const float*)d_in[2];
    const float* b1  = (const float*)d_in[3];
    const float* W2  = (const float*)d_in[4];
    const float* b2  = (const float*)d_in[5];
    const float* Wm1 = (const float*)d_in[6];
    const float* bm1 = (const float*)d_in[7];
    const float* Wm2 = (const float*)d_in[8];
    const float* bm2 = (const float*)d_in[9];
    float* out = (float*)d_out;

    int N = in_sizes[0] / 3;
    int E = in_sizes[1] / 2;
    const int* src = ei;
    const int* dst = ei + E;
    int NBK = (N + SPAN - 1) / SPAN;   // 782

    uintptr_t p = (uintptr_t)d_ws;
    auto carve = [&](size_t bytes) -> void* {
        p = (p + 255) & ~(uintptr_t)255;
        void* r = (void*)p;
        p += bytes;
        return r;
    };
    __half*   a2h     = (__half*)carve((size_t)N * 64 * 2);    // colb aliases a2h+s1h
    __half*   s1h     = (__half*)carve((size_t)N * 64 * 2);
    int*      cursor  = (int*)carve((size_t)NBK * 4);
    int*      row_ptr = (int*)carve((size_t)(N + 1) * 4);
    float*    dis     = (float*)carve((size_t)N * 4);
    __half*   sxh     = (__half*)carve((size_t)N * 8);
    int*      col     = (int*)carve((size_t)E * 4);
    __half*   W2t     = (__half*)carve(64 * 64 * 2);
    __half*   Wm1t    = (__half*)carve(128 * 64 * 2);
    __half*   Wm2p    = (__half*)carve(4 * 64 * 8 * 2);
    unsigned* colb = (unsigned*)a2h;   // dead after csr_sort; rewritten later

    int nChunks = (E + CH - 1) / CH;          // 391
    int waveBlocks3  = (N + 3) / 4;           // agg3: 1 node/wave
    int waveBlocks64 = (N + 7) / 8;           // agg64: 2 nodes/wave
    int nTiles = (N + 63) / 64;               // h1: 64-node tiles

    hipMemsetAsync(cursor, 0, (size_t)NBK * 4, stream);
    scatter_kernel<<<nChunks + 1, 512, 0, stream>>>(src, dst, cursor, colb,
        W2, Wm1, Wm2, W2t, Wm1t, Wm2p, E, NBK, nChunks);
    csr_sort_kernel<<<NBK, 256, 0, stream>>>(colb, cursor, x, row_ptr, col, dis, sxh, N, NBK);
    agg3_kernel<<<waveBlocks3, 256, 0, stream>>>(sxh, row_ptr, col, dis, W1, b1, s1h, N);
    agg64_kernel<<<waveBlocks64, 256, 0, stream>>>((const __half2*)s1h, row_ptr, col, dis,
                                                   (__half2*)a2h, N);
    h1_kernel<<<nTiles, 256, 0, stream>>>(a2h, W2t, b2, Wm1t, bm1, Wm2p, bm2, out, N);
}

// Round 14
// 243.742 us; speedup vs baseline: 1.3830x; 1.0123x over previous
//
#include <hip/hip_runtime.h>
#include <hip/hip_fp16.h>
#include <math.h>

// ---------------------------------------------------------------------------
// GNN pool: 2x GCNConv(elu) + MLP(128) + Linear(15) + softmax
// N=100000, E=3200000, IN=3, HID=64, MLP_HID=128, K=15, fp32 in/out.
//
// Round-14 pipeline (6 dispatches incl. memset):
//   memset cursor -> scatter512 (+prep block) -> csr_sort512 (in-place
//   padded sort in colb, rp2=(start,end), uint4 edge IO) -> agg3 (2 nodes/
//   wave: mean deg 32 filled a half-wave, 64-lane version idled 50%)
//   -> agg64 (r9 loads + __hadd2 edge-pairing: 32->20 VALU/8 edges)
//   -> h1 (all-MFMA + shfl softmax, r13)
//
// r13 insight: agg64 delivered 11.3 B/cyc/CU (m13 per-CU ceiling) while L2
// at 20% / HBM at 40% of their aggregates -> CU-side request-service bound,
// VALU 44% alongside. This round tests whether trimming VALU (holding the
// load pattern fixed, unlike r11's confounded attempt) buys anything.
// ---------------------------------------------------------------------------

#define SPAN 128          // nodes per bucket
#define CAP  4608         // bucket capacity (mean 4092 + ~8 sigma)
#define CH   8192         // edges per scatter chunk (391 chunks)
#define EPT  16           // edges per thread in scatter (512 threads)
#define H2P  88           // h2s row pad (halfs)
#define MSP2 136          // ms row pad (halfs)

typedef _Float16 v8hf __attribute__((ext_vector_type(8)));
typedef float    v4f  __attribute__((ext_vector_type(4)));

__device__ __forceinline__ float elu(float v) { return v > 0.f ? v : expm1f(v); }

// ---- scatter (512 thr): edges -> buckets by dst>>7; last block = weight prep ----
__global__ __launch_bounds__(512) void scatter_kernel(const int* __restrict__ src,
    const int* __restrict__ dst, int* __restrict__ cursor, unsigned* __restrict__ colb,
    const float* __restrict__ W2, const float* __restrict__ Wm1,
    const float* __restrict__ Wm2, __half* __restrict__ W2t,
    __half* __restrict__ Wm1t, __half* __restrict__ Wm2p,
    int E, int NBK, int nChunks) {
    int tid = threadIdx.x;
    if ((int)blockIdx.x == nChunks) {   // ---- prep block ----
        for (int i = tid; i < 64 * 64; i += 512) {
            int f = i >> 6, k = i & 63;
            W2t[f * 64 + k] = __float2half(W2[k * 64 + f]);
        }
        for (int i = tid; i < 128 * 64; i += 512) {
            int j = i >> 6, f = i & 63;
            Wm1t[j * 64 + f] = __float2half(Wm1[f * 128 + j]);
        }
        for (int i = tid; i < 4 * 64 * 8; i += 512) {
            int j = i & 7, l = (i >> 3) & 63, t = i >> 9;
            int k = t * 32 + (l >> 4) * 8 + j;
            int c = l & 15;
            Wm2p[i] = (c < 15) ? __float2half(Wm2[k * 15 + c]) : __half(0.f);
        }
        return;
    }
    __shared__ int hist[1024];
    __shared__ unsigned gb[1024];
    int chunk = blockIdx.x;
    for (int i = tid; i < NBK; i += 512) hist[i] = 0;
    __syncthreads();
    int base = chunk * CH;
    int cnt = min(CH, E - base);
    unsigned br[EPT], dt[EPT];
#pragma unroll
    for (int j = 0; j < EPT; ++j) {
        int idx = j * 512 + tid;
        br[j] = 0xFFFFFFFFu;
        if (idx < cnt) {
            int e = base + idx;
            int s = src[e], d = dst[e];
            int b = d >> 7;
            int r = atomicAdd(&hist[b], 1);
            br[j] = ((unsigned)b << 13) | (unsigned)r;   // b<1024(10b), r<8192(13b)
            dt[j] = ((unsigned)(d & 127) << 17) | (unsigned)s;
        }
    }
    __syncthreads();
    for (int b = tid; b < NBK; b += 512) {
        int c = hist[b];
        gb[b] = (unsigned)(b * CAP) + (c ? (unsigned)atomicAdd(&cursor[b], c) : 0u);
    }
    __syncthreads();
#pragma unroll
    for (int j = 0; j < EPT; ++j) {
        if (br[j] != 0xFFFFFFFFu) {
            int b = br[j] >> 13;
            int r = br[j] & 8191;
            unsigned pos = gb[b] + (unsigned)r;
            if (pos < (unsigned)(b + 1) * CAP) colb[pos] = dt[j];
        }
    }
}

// ---- per-bucket counting sort IN PLACE (padded layout), rp2, dis, sxh ----
__global__ __launch_bounds__(512) void csr_sort_kernel(unsigned* __restrict__ colb,
    const int* __restrict__ cursor, const float* __restrict__ x,
    uint2* __restrict__ rp2, float* __restrict__ dis, __half* __restrict__ sxh,
    int N) {
    __shared__ __align__(16) unsigned ebuf[CAP];
    __shared__ __align__(16) int sbuf[CAP];
    __shared__ int cnt[SPAN], pref[SPAN], fill[SPAN];
    int b = blockIdx.x, tid = threadIdx.x;
    int n = min(cursor[b], CAP);
    size_t base = (size_t)b * CAP;
    if (tid < SPAN) cnt[tid] = 0;
    int n4 = n >> 2;
    for (int k = tid; k < n4; k += 512)
        *(uint4*)(ebuf + 4 * k) = *(const uint4*)(colb + base + 4 * k);
    for (int i = (n4 << 2) + tid; i < n; i += 512) ebuf[i] = colb[base + i];
    __syncthreads();
    for (int i = tid; i < n; i += 512) atomicAdd(&cnt[(ebuf[i] >> 17) & 127], 1);
    __syncthreads();
    if (tid < SPAN) pref[tid] = cnt[tid];
    __syncthreads();
    for (int off = 1; off < SPAN; off <<= 1) {
        int xv = (tid < SPAN && tid >= off) ? pref[tid - off] : 0;
        __syncthreads();
        if (tid < SPAN) pref[tid] += xv;
        __syncthreads();
    }
    if (tid < SPAN) {
        int ex = pref[tid] - cnt[tid];
        fill[tid] = ex;
        int node = b * SPAN + tid;
        if (node < N) {
            uint2 rp;
            rp.x = (unsigned)(base + ex);
            rp.y = (unsigned)(base + ex + cnt[tid]);
            rp2[node] = rp;
            float r = rsqrtf((float)(cnt[tid] + 1));
            dis[node] = r;
            __half2 h0 = __floats2half2_rn(r * x[node * 3 + 0], r * x[node * 3 + 1]);
            __half2 h1 = __floats2half2_rn(r * x[node * 3 + 2], 0.f);
            uint2 w; w.x = *(unsigned*)&h0; w.y = *(unsigned*)&h1;
            *(uint2*)(sxh + (size_t)node * 4) = w;
        }
    }
    __syncthreads();
    for (int i = tid; i < n; i += 512) {
        unsigned e = ebuf[i];
        int pos = atomicAdd(&fill[(e >> 17) & 127], 1);
        sbuf[pos] = (int)(e & 0x1FFFF);
    }
    __syncthreads();
    for (int k = tid; k < n4; k += 512)
        *(uint4*)(colb + base + 4 * k) = *(const uint4*)(sbuf + 4 * k);
    for (int i = (n4 << 2) + tid; i < n; i += 512) colb[base + i] = (unsigned)sbuf[i];
}

// ---- layer 1: 2 nodes/wave (32 lanes each), 8B gathers; s1h fp16 ----
__global__ void agg3_kernel(const __half* __restrict__ sxh, const uint2* __restrict__ rp2,
                            const unsigned* __restrict__ colb, const float* __restrict__ dis,
                            const float* __restrict__ W1, const float* __restrict__ b1,
                            __half* __restrict__ s1h, int N) {
    int wave = (blockIdx.x * blockDim.x + threadIdx.x) >> 6;
    int lane = threadIdx.x & 63;
    int hl = lane & 31;
    int d = wave * 2 + (lane >> 5);
    bool act = d < N;
    int start = 0, end = 0;
    if (act) { uint2 rp = rp2[d]; start = (int)rp.x; end = (int)rp.y; }
    float a0 = 0.f, a1 = 0.f, a2v = 0.f;
    for (int i = start + hl; i < end; i += 32) {
        uint2 rq = *(const uint2*)(sxh + (size_t)colb[i] * 4);
        float2 u0 = __half22float2(*(__half2*)&rq.x);
        float2 u1 = __half22float2(*(__half2*)&rq.y);
        a0 += u0.x; a1 += u0.y; a2v += u1.x;
    }
#pragma unroll
    for (int off = 16; off; off >>= 1) {
        a0  += __shfl_xor(a0, off);
        a1  += __shfl_xor(a1, off);
        a2v += __shfl_xor(a2v, off);
    }
    if (act) {
        uint2 rq = *(const uint2*)(sxh + (size_t)d * 4);   // self loop
        float2 u0 = __half22float2(*(__half2*)&rq.x);
        float2 u1 = __half22float2(*(__half2*)&rq.y);
        a0 += u0.x; a1 += u0.y; a2v += u1.x;
        float r = dis[d];
        float v0 = r * (a0 * W1[hl]      + a1 * W1[64 + hl]      + a2v * W1[128 + hl])      + b1[hl];
        float v1 = r * (a0 * W1[32 + hl] + a1 * W1[96 + hl]      + a2v * W1[160 + hl])      + b1[32 + hl];
        s1h[(size_t)d * 64 + hl]      = __float2half(r * elu(v0));
        s1h[(size_t)d * 64 + 32 + hl] = __float2half(r * elu(v1));
    }
}

// ---- layer 2: r9 loads + __hadd2 edge pairing; fp32 accum; fp16 out ----
__global__ void agg64_kernel(const __half2* __restrict__ s1h, const uint2* __restrict__ rp2,
                             const unsigned* __restrict__ colb, const float* __restrict__ dis,
                             __half2* __restrict__ a2h, int N) {
    int wave = (blockIdx.x * blockDim.x + threadIdx.x) >> 6;
    int lane = threadIdx.x & 63;
    int hl = lane & 31;
    int d = wave * 2 + (lane >> 5);
    bool act = d < N;
    int start = 0, end = 0;
    if (act) { uint2 rp = rp2[d]; start = (int)rp.x; end = (int)rp.y; }
    float a0x = 0.f, a0y = 0.f, a1x = 0.f, a1y = 0.f;
    float a2x = 0.f, a2y = 0.f, a3x = 0.f, a3y = 0.f;
    if (act) {   // self loop
        float2 v = __half22float2(s1h[(size_t)d * 32 + hl]);
        a0x = v.x; a0y = v.y;
    }
    int i = start;
    for (; i + 7 < end; i += 8) {
        int c0 = (int)colb[i],     c1 = (int)colb[i + 1];
        int c2 = (int)colb[i + 2], c3 = (int)colb[i + 3];
        int c4 = (int)colb[i + 4], c5 = (int)colb[i + 5];
        int c6 = (int)colb[i + 6], c7 = (int)colb[i + 7];
        __half2 v0 = s1h[(size_t)c0 * 32 + hl];
        __half2 v1 = s1h[(size_t)c1 * 32 + hl];
        __half2 v2 = s1h[(size_t)c2 * 32 + hl];
        __half2 v3 = s1h[(size_t)c3 * 32 + hl];
        __half2 v4 = s1h[(size_t)c4 * 32 + hl];
        __half2 v5 = s1h[(size_t)c5 * 32 + hl];
        __half2 v6 = s1h[(size_t)c6 * 32 + hl];
        __half2 v7 = s1h[(size_t)c7 * 32 + hl];
        float2 p0 = __half22float2(__hadd2(v0, v1));
        float2 p1 = __half22float2(__hadd2(v2, v3));
        float2 p2 = __half22float2(__hadd2(v4, v5));
        float2 p3 = __half22float2(__hadd2(v6, v7));
        a0x += p0.x; a0y += p0.y; a1x += p1.x; a1y += p1.y;
        a2x += p2.x; a2y += p2.y; a3x += p3.x; a3y += p3.y;
    }
    for (; i < end; ++i) {
        float2 v = __half22float2(s1h[(size_t)colb[i] * 32 + hl]);
        a0x += v.x; a0y += v.y;
    }
    if (act) {
        float r = dis[d];
        float ox = r * ((a0x + a1x) + (a2x + a3x));
        float oy = r * ((a0y + a1y) + (a2y + a3y));
        a2h[(size_t)d * 32 + hl] = __floats2half2_rn(ox, oy);
    }
}

// ---- h1 (all-MFMA): out = softmax(elu(elu(a2h@W2)@Wm1)@Wm2) ----
__global__ __launch_bounds__(256) void h1_kernel(const __half* __restrict__ a2h,
    const __half* __restrict__ W2t, const float* __restrict__ b2g,
    const __half* __restrict__ Wm1t, const float* __restrict__ bm1g,
    const __half* __restrict__ Wm2p, const float* __restrict__ bm2g,
    float* __restrict__ out, int N) {
    __shared__ __align__(16) __half h2s[64 * H2P];   // 11.3 KB
    __shared__ __align__(16) __half ms[64 * MSP2];   // 17.4 KB
    int tid = threadIdx.x;
    int wave = tid >> 6, lane = tid & 63;
    int q = lane >> 4, l16 = lane & 15;
    int base = blockIdx.x * 64;

    v8hf wc[4];
#pragma unroll
    for (int t = 0; t < 4; ++t)
        wc[t] = *(const v8hf*)(Wm2p + ((size_t)(t * 64 + lane)) * 8);
    float bbc = (l16 < 15) ? bm2g[l16] : 0.f;

    // ---- stage A: D[m=node16][n=f] = a2h @ W2 ----
    {
        int nodeRow = base + wave * 16 + l16;
        size_t arow = (size_t)min(nodeRow, N - 1) * 64;
        v8hf af0 = *(const v8hf*)(a2h + arow + q * 8);
        v8hf af1 = *(const v8hf*)(a2h + arow + 32 + q * 8);
#pragma unroll
        for (int fb = 0; fb < 4; ++fb) {
            float bb = b2g[fb * 16 + l16];
            v4f acc = {bb, bb, bb, bb};
            v8hf b0 = *(const v8hf*)(W2t + (fb * 16 + l16) * 64 + q * 8);
            v8hf b1 = *(const v8hf*)(W2t + (fb * 16 + l16) * 64 + 32 + q * 8);
            acc = __builtin_amdgcn_mfma_f32_16x16x32_f16(af0, b0, acc, 0, 0, 0);
            acc = __builtin_amdgcn_mfma_f32_16x16x32_f16(af1, b1, acc, 0, 0, 0);
#pragma unroll
            for (int r = 0; r < 4; ++r)
                h2s[(wave * 16 + q * 4 + r) * H2P + fb * 16 + l16] =
                    __float2half(elu(acc[r]));
        }
    }
    __syncthreads();
    // ---- stage B: D[m=node16][n=j] = h2 @ Wm1 ----
    {
        int arow = (wave * 16 + l16) * H2P;
        v8hf af0 = *(const v8hf*)(h2s + arow + q * 8);
        v8hf af1 = *(const v8hf*)(h2s + arow + 32 + q * 8);
#pragma unroll
        for (int jb = 0; jb < 8; ++jb) {
            float bb = bm1g[jb * 16 + l16];
            v4f acc = {bb, bb, bb, bb};
            v8hf b0 = *(const v8hf*)(Wm1t + (jb * 16 + l16) * 64 + q * 8);
            v8hf b1 = *(const v8hf*)(Wm1t + (jb * 16 + l16) * 64 + 32 + q * 8);
            acc = __builtin_amdgcn_mfma_f32_16x16x32_f16(af0, b0, acc, 0, 0, 0);
            acc = __builtin_amdgcn_mfma_f32_16x16x32_f16(af1, b1, acc, 0, 0, 0);
#pragma unroll
            for (int r = 0; r < 4; ++r)
                ms[(wave * 16 + q * 4 + r) * MSP2 + jb * 16 + l16] =
                    __float2half(elu(acc[r]));
        }
    }
    __syncthreads();
    // ---- stage C: D[m=node16][n=class16] = m @ Wm2 (K=128), shfl softmax ----
    {
        int arow = (wave * 16 + l16) * MSP2;
        v4f accC = {bbc, bbc, bbc, bbc};
#pragma unroll
        for (int t = 0; t < 4; ++t) {
            v8hf a = *(const v8hf*)(ms + arow + t * 32 + q * 8);
            accC = __builtin_amdgcn_mfma_f32_16x16x32_f16(a, wc[t], accC, 0, 0, 0);
        }
#pragma unroll
        for (int r = 0; r < 4; ++r) {
            float lg = (l16 < 15) ? accC[r] : -1e30f;
            float mx = lg;
            mx = fmaxf(mx, __shfl_xor(mx, 1));
            mx = fmaxf(mx, __shfl_xor(mx, 2));
            mx = fmaxf(mx, __shfl_xor(mx, 4));
            mx = fmaxf(mx, __shfl_xor(mx, 8));
            float ex = (l16 < 15) ? __expf(lg - mx) : 0.f;
            float sden = ex;
            sden += __shfl_xor(sden, 1);
            sden += __shfl_xor(sden, 2);
            sden += __shfl_xor(sden, 4);
            sden += __shfl_xor(sden, 8);
            int node = base + wave * 16 + q * 4 + r;
            if (l16 < 15 && node < N)
                out[(size_t)node * 15 + l16] = ex / sden;
        }
    }
}

extern "C" void kernel_launch(void* const* d_in, const int* in_sizes, int n_in,
                              void* d_out, int out_size, void* d_ws, size_t ws_size,
                              hipStream_t stream) {
    const float* x   = (const float*)d_in[0];
    const int*   ei  = (const int*)d_in[1];
    const float* W1  = (const float*)d_in[2];
    const float* b1  = (const float*)d_in[3];
    const float* W2  = (const float*)d_in[4];
    const float* b2  = (const float*)d_in[5];
    const float* Wm1 = (const float*)d_in[6];
    const float* bm1 = (const float*)d_in[7];
    const float* Wm2 = (const float*)d_in[8];
    const float* bm2 = (const float*)d_in[9];
    float* out = (float*)d_out;

    int N = in_sizes[0] / 3;
    int E = in_sizes[1] / 2;
    const int* src = ei;
    const int* dst = ei + E;
    int NBK = (N + SPAN - 1) / SPAN;   // 782

    uintptr_t p = (uintptr_t)d_ws;
    auto carve = [&](size_t bytes) -> void* {
        p = (p + 255) & ~(uintptr_t)255;
        void* r = (void*)p;
        p += bytes;
        return r;
    };
    unsigned* colb    = (unsigned*)carve((size_t)NBK * CAP * 4);   // live thru agg64
    __half*   a2h     = (__half*)carve((size_t)N * 64 * 2);
    __half*   s1h     = (__half*)carve((size_t)N * 64 * 2);
    int*      cursor  = (int*)carve((size_t)NBK * 4);
    uint2*    rp2     = (uint2*)carve((size_t)N * 8);
    float*    dis     = (float*)carve((size_t)N * 4);
    __half*   sxh     = (__half*)carve((size_t)N * 8);
    __half*   W2t     = (__half*)carve(64 * 64 * 2);
    __half*   Wm1t    = (__half*)carve(128 * 64 * 2);
    __half*   Wm2p    = (__half*)carve(4 * 64 * 8 * 2);

    int nChunks = (E + CH - 1) / CH;          // 391
    int aggBlocks = (N + 7) / 8;              // 2 nodes/wave, 4 waves/block
    int nTiles = (N + 63) / 64;               // h1: 64-node tiles

    hipMemsetAsync(cursor, 0, (size_t)NBK * 4, stream);
    scatter_kernel<<<nChunks + 1, 512, 0, stream>>>(src, dst, cursor, colb,
        W2, Wm1, Wm2, W2t, Wm1t, Wm2p, E, NBK, nChunks);
    csr_sort_kernel<<<NBK, 512, 0, stream>>>(colb, cursor, x, rp2, dis, sxh, N);
    agg3_kernel<<<aggBlocks, 256, 0, stream>>>(sxh, rp2, colb, dis, W1, b1, s1h, N);
    agg64_kernel<<<aggBlocks, 256, 0, stream>>>((const __half2*)s1h, rp2, colb, dis,
                                                (__half2*)a2h, N);
    h1_kernel<<<nTiles, 256, 0, stream>>>(a2h, W2t, b2, Wm1t, bm1, Wm2p, bm2, out, N);
}